// Round 2
// baseline (393.610 us; speedup 1.0000x reference)
//
#include <hip/hip_runtime.h>
#include <hip/hip_bf16.h>
#include <math.h>

// ---------------------------------------------------------------------------
// CrossModalityMultiHeadAttention  (MI355X / gfx950)
// Round 9: ONE persistent mega-kernel. Theory: ~130us of the 190us total is
// inter-dispatch overhead (5 dispatches, each <43us, sum-of-physics ~60us).
// All stages in one launch, separated by device-wide software barriers:
//   S0 prep: casts + ranges + 8 weight transposes + mapw cast + parallel fb
//   S1 fold GEMMs (FqT/FkT/FvT = q1T/k1T/v1T @ mapw^T)   [36 tiles]
//   S2 qkv GEMMs (6 jobs, head side uses folded weights) [768 tiles]
//   S3 attention (both sides)                            [1024 blocks]
//   S4 output projections                                [256 tiles]
// Deadlock safety: __launch_bounds__(256,2) guarantees >=2 blocks/CU;
// launcher sizes grid = min(768, occupancy*CUs); all stages grid-stride.
// Barrier counters in ws, zeroed via hipMemsetAsync (graph-capturable).
// gemm/attn inner loops byte-identical to round-7/8 proven code.
// ---------------------------------------------------------------------------

typedef __bf16 bf16x8 __attribute__((ext_vector_type(8)));
typedef float  f32x4  __attribute__((ext_vector_type(4)));

#define HID 512
#define NTOK 4096

#define AS1(p) ((const __attribute__((address_space(1))) void*)(p))
#define AS3(p) ((__attribute__((address_space(3))) void*)(p))

struct MegaArgs {
    // inputs
    const float* h_head; const float* h_tail;
    const int* bh; const int* bt;
    const float* map_w; const float* map_b;
    const float* wsrc[8];       // q1,k1,v1,q2,k2,v2,d1,d2 fp32 [512][512]
    const float* qkvb1[3];      // q1_b,k1_b,v1_b
    const float* b2[3];         // q2_b,k2_b,v2_b
    const float* d1_b; const float* d2_b;
    // workspace
    __bf16* wT[8];              // transposed bf16 [512][512]
    __bf16* hh_bf;              // [4096][320]
    __bf16* ht_bf;              // [4096][512]
    __bf16* mapw_bf;            // [384][512] (rows>=300 zero)
    __bf16* F[3];               // FqT,FkT,FvT [512][320]
    __bf16* qh; __bf16* kh; __bf16* vh;
    __bf16* qt; __bf16* kt; __bf16* vt;
    __bf16* ctxh; __bf16* ctxt;
    float* fb;                  // [3][512]
    int* ranges;                // 256 ints
    float* out;
    int* bar;                   // 4 counters @ 16-int stride
    int nblk;
};

// ------------------------- device-wide barrier -----------------------------
__device__ __forceinline__ void grid_barrier(int* cnt, int nblk) {
    __syncthreads();            // all waves done; vm drained at s_barrier
    __threadfence();            // release: write back dirty L2 (agent scope)
    if (threadIdx.x == 0) {
        __hip_atomic_fetch_add(cnt, 1, __ATOMIC_RELAXED, __HIP_MEMORY_SCOPE_AGENT);
        while (__hip_atomic_load(cnt, __ATOMIC_RELAXED, __HIP_MEMORY_SCOPE_AGENT) < nblk)
            __builtin_amdgcn_s_sleep(8);
    }
    __syncthreads();
    __threadfence();            // acquire: invalidate stale L1/L2
}

// ------------------------------ GEMM tile ----------------------------------
// C[row][col] = sum_k A[row][k]*W[col][k] + bias[col]; identical main loop to
// round-7 (double-buffered global_load_lds + XOR k-chunk swizzle).
template <typename TC>
__device__ __forceinline__ void gemm_tile(
    const __bf16* __restrict__ A, const __bf16* __restrict__ W,
    const float* __restrict__ bias, TC* __restrict__ C,
    int Kp, int ldC, int Ncol, int bx, int by, char* SMEM)
{
    __bf16* As = (__bf16*)SMEM;            // [2][4096]
    __bf16* Bs = (__bf16*)(SMEM + 16384);  // [2][4096]

    const int tid  = threadIdx.x;
    const int wave = tid >> 6;
    const int lane = tid & 63;
    const int quad = lane >> 4;
    const int l16  = lane & 15;
    const int wy   = wave >> 1;
    const int wx   = wave & 1;
    const int rowBase = by * 128;
    const int colBase = bx * 128;

    const int s_row = tid >> 2;
    const int s_kc  = ((tid & 3) ^ ((s_row >> 1) & 3)) * 8;

    const __bf16* gA = A + (size_t)(rowBase + s_row) * Kp + s_kc;
    const __bf16* gB = W + (size_t)(colBase + s_row) * Kp + s_kc;
    const int waveOff = wave * 512;

    f32x4 acc[4][4] = {};
    const int nk = Kp >> 5;

    __syncthreads();   // guard LDS reuse vs previous tile/stage

    __builtin_amdgcn_global_load_lds(AS1(gA),                   AS3(&As[waveOff]),        16, 0, 0);
    __builtin_amdgcn_global_load_lds(AS1(gA + (size_t)64 * Kp), AS3(&As[2048 + waveOff]), 16, 0, 0);
    __builtin_amdgcn_global_load_lds(AS1(gB),                   AS3(&Bs[waveOff]),        16, 0, 0);
    __builtin_amdgcn_global_load_lds(AS1(gB + (size_t)64 * Kp), AS3(&Bs[2048 + waveOff]), 16, 0, 0);

    for (int i = 0; i < nk; ++i) {
        const int cur = i & 1;
        __syncthreads();   // drains tile i's loads; prev reads of buf[cur^1] done

        if (i + 1 < nk) {
            const int kt = (i + 1) * 32;
            const int nx = cur ^ 1;
            __builtin_amdgcn_global_load_lds(AS1(gA + kt),                   AS3(&As[nx * 4096 + waveOff]),        16, 0, 0);
            __builtin_amdgcn_global_load_lds(AS1(gA + kt + (size_t)64 * Kp), AS3(&As[nx * 4096 + 2048 + waveOff]), 16, 0, 0);
            __builtin_amdgcn_global_load_lds(AS1(gB + kt),                   AS3(&Bs[nx * 4096 + waveOff]),        16, 0, 0);
            __builtin_amdgcn_global_load_lds(AS1(gB + kt + (size_t)64 * Kp), AS3(&Bs[nx * 4096 + 2048 + waveOff]), 16, 0, 0);
        }

        bf16x8 ar[4], br[4];
        #pragma unroll
        for (int ii = 0; ii < 4; ++ii) {
            const int ra = wy * 64 + ii * 16 + l16;
            ar[ii] = *(const bf16x8*)&As[cur * 4096 + ra * 32 + ((quad ^ ((ra >> 1) & 3)) << 3)];
        }
        #pragma unroll
        for (int jj = 0; jj < 4; ++jj) {
            const int rb = wx * 64 + jj * 16 + l16;
            br[jj] = *(const bf16x8*)&Bs[cur * 4096 + rb * 32 + ((quad ^ ((rb >> 1) & 3)) << 3)];
        }
        #pragma unroll
        for (int ii = 0; ii < 4; ++ii)
            #pragma unroll
            for (int jj = 0; jj < 4; ++jj)
                acc[ii][jj] = __builtin_amdgcn_mfma_f32_16x16x32_bf16(ar[ii], br[jj], acc[ii][jj], 0, 0, 0);
    }

    // epilogue: C/D layout col=l16, row=quad*4+reg
    #pragma unroll
    for (int jj = 0; jj < 4; ++jj) {
        int col = colBase + wx * 64 + jj * 16 + l16;
        if (col < Ncol) {
            float bv = bias ? bias[col] : 0.f;
            #pragma unroll
            for (int ii = 0; ii < 4; ++ii) {
                #pragma unroll
                for (int r = 0; r < 4; ++r) {
                    int row = rowBase + wy * 64 + ii * 16 + quad * 4 + r;
                    C[(size_t)row * ldC + col] = (TC)(acc[ii][jj][r] + bv);
                }
            }
        }
    }
}

// ------------------------- MFMA flash attention ----------------------------
__device__ void attn_block(const MegaArgs& a, int h, int b, int z, char* SMEM)
{
    typedef __bf16 row72[72];
    row72* Qs = (row72*)SMEM;
    row72* Ks = (row72*)(SMEM + 9216);
    row72* Vt = (row72*)(SMEM + 18432);
    row72* Ps = (row72*)(SMEM + 27648);

    const __bf16* Q    = z ? a.qt : a.qh;
    const __bf16* Kg   = z ? a.kh : a.kt;
    const __bf16* Vres = z ? a.vt : a.vh;
    const __bf16* Vctx = z ? a.vh : a.vt;
    __bf16* Out        = z ? a.ctxt : a.ctxh;
    const int* ranges  = a.ranges;
    const int* qstart  = z ? ranges + 128 : ranges;
    const int* qend    = z ? ranges + 192 : ranges + 64;
    const int* kstart  = z ? ranges       : ranges + 128;
    const int* kend    = z ? ranges + 64  : ranges + 192;
    const int Nq = NTOK, Nk = NTOK;

    const int qs = qstart[b], qe = qend[b];
    const int ts = kstart[b], te = kend[b];
    const int nq = qe - qs, nk = te - ts;
    if (nq <= 0) return;

    const int tid  = threadIdx.x;
    const int wave = tid >> 6;
    const int lane = tid & 63;
    const int quad = lane >> 4;
    const int l16  = lane & 15;
    const int srow = tid >> 2;
    const int scol = (tid & 3) * 16;

    if (nk <= 0) {
        __syncthreads();
        float* meanv = (float*)Qs;
        if (tid < 64) {
            float s = 0.f;
            for (int m = 0; m < Nk; ++m)
                s += (float)Vctx[(size_t)m * HID + h * 64 + tid];
            meanv[tid] = s / (float)Nk;
        }
        __syncthreads();
        int d = tid & 63;
        for (int r = qs + (tid >> 6); r < qe; r += 4) {
            size_t off = (size_t)r * HID + h * 64 + d;
            Out[off] = (__bf16)((float)Vres[off] + meanv[d]);
        }
        return;
    }

    for (int qc = 0; qc < nq; qc += 64) {
        __syncthreads();
        {
            int qg = min(qs + qc + srow, Nq - 1);
            const __bf16* src = Q + (size_t)qg * HID + h * 64 + scol;
            *(bf16x8*)&Qs[srow][scol]     = *(const bf16x8*)src;
            *(bf16x8*)&Qs[srow][scol + 8] = *(const bf16x8*)(src + 8);
        }
        __syncthreads();
        bf16x8 aq0 = *(const bf16x8*)&Qs[wave * 16 + l16][quad * 8];
        bf16x8 aq1 = *(const bf16x8*)&Qs[wave * 16 + l16][32 + quad * 8];

        f32x4 O[4] = {};
        float Mx[4], L[4];
        #pragma unroll
        for (int r = 0; r < 4; ++r) { Mx[r] = -__builtin_inff(); L[r] = 0.f; }

        for (int kc = 0; kc < nk; kc += 64) {
            __syncthreads();
            {
                int kg = min(ts + kc + srow, Nk - 1);
                const __bf16* ksrc = Kg + (size_t)kg * HID + h * 64 + scol;
                *(bf16x8*)&Ks[srow][scol]     = *(const bf16x8*)ksrc;
                *(bf16x8*)&Ks[srow][scol + 8] = *(const bf16x8*)(ksrc + 8);
                const __bf16* vsrc = Vctx + (size_t)kg * HID + h * 64 + scol;
                bf16x8 v0 = *(const bf16x8*)vsrc;
                bf16x8 v1 = *(const bf16x8*)(vsrc + 8);
                #pragma unroll
                for (int j = 0; j < 8; ++j) {
                    Vt[scol + j][srow]     = v0[j];
                    Vt[scol + 8 + j][srow] = v1[j];
                }
            }
            __syncthreads();

            f32x4 S[4] = {};
            #pragma unroll
            for (int c = 0; c < 4; ++c) {
                bf16x8 bk0 = *(const bf16x8*)&Ks[c * 16 + l16][quad * 8];
                bf16x8 bk1 = *(const bf16x8*)&Ks[c * 16 + l16][32 + quad * 8];
                S[c] = __builtin_amdgcn_mfma_f32_16x16x32_bf16(aq0, bk0, S[c], 0, 0, 0);
                S[c] = __builtin_amdgcn_mfma_f32_16x16x32_bf16(aq1, bk1, S[c], 0, 0, 0);
            }

            #pragma unroll
            for (int c = 0; c < 4; ++c) {
                bool valid = (ts + kc + c * 16 + l16) < te;
                #pragma unroll
                for (int r = 0; r < 4; ++r)
                    S[c][r] = valid ? S[c][r] * 0.125f : -__builtin_inff();
            }

            float cm[4], ps[4], alpha[4];
            #pragma unroll
            for (int r = 0; r < 4; ++r) {
                float v = fmaxf(fmaxf(S[0][r], S[1][r]), fmaxf(S[2][r], S[3][r]));
                v = fmaxf(v, __shfl_xor(v, 1, 64));
                v = fmaxf(v, __shfl_xor(v, 2, 64));
                v = fmaxf(v, __shfl_xor(v, 4, 64));
                v = fmaxf(v, __shfl_xor(v, 8, 64));
                cm[r] = v;
            }
            #pragma unroll
            for (int r = 0; r < 4; ++r) {
                float nM = fmaxf(Mx[r], cm[r]);
                alpha[r] = __expf(Mx[r] - nM);
                Mx[r] = nM;
                ps[r] = 0.f;
            }
            #pragma unroll
            for (int c = 0; c < 4; ++c)
                #pragma unroll
                for (int r = 0; r < 4; ++r) {
                    float p = __expf(S[c][r] - Mx[r]);
                    S[c][r] = p;
                    ps[r] += p;
                }
            #pragma unroll
            for (int r = 0; r < 4; ++r) {
                float v = ps[r];
                v += __shfl_xor(v, 1, 64);
                v += __shfl_xor(v, 2, 64);
                v += __shfl_xor(v, 4, 64);
                v += __shfl_xor(v, 8, 64);
                L[r] = L[r] * alpha[r] + v;
            }
            #pragma unroll
            for (int c = 0; c < 4; ++c)
                #pragma unroll
                for (int r = 0; r < 4; ++r)
                    O[c][r] *= alpha[r];

            #pragma unroll
            for (int c = 0; c < 4; ++c)
                #pragma unroll
                for (int r = 0; r < 4; ++r)
                    Ps[wave * 16 + quad * 4 + r][c * 16 + l16] = (__bf16)S[c][r];
            __syncthreads();

            bf16x8 ap0 = *(const bf16x8*)&Ps[wave * 16 + l16][quad * 8];
            bf16x8 ap1 = *(const bf16x8*)&Ps[wave * 16 + l16][32 + quad * 8];
            #pragma unroll
            for (int c = 0; c < 4; ++c) {
                bf16x8 bv0 = *(const bf16x8*)&Vt[c * 16 + l16][quad * 8];
                bf16x8 bv1 = *(const bf16x8*)&Vt[c * 16 + l16][32 + quad * 8];
                O[c] = __builtin_amdgcn_mfma_f32_16x16x32_bf16(ap0, bv0, O[c], 0, 0, 0);
                O[c] = __builtin_amdgcn_mfma_f32_16x16x32_bf16(ap1, bv1, O[c], 0, 0, 0);
            }
        }

        #pragma unroll
        for (int c = 0; c < 4; ++c) {
            int d = h * 64 + c * 16 + l16;
            #pragma unroll
            for (int r = 0; r < 4; ++r) {
                int qrow = qs + qc + wave * 16 + quad * 4 + r;
                if (qrow < qe) {
                    size_t off = (size_t)qrow * HID + d;
                    Out[off] = (__bf16)((float)Vres[off] + O[c][r] / L[r]);
                }
            }
        }
    }
}

// ------------------------------ mega kernel --------------------------------
__global__ __launch_bounds__(256, 2) void mega(MegaArgs a) {
    __shared__ __align__(16) char SMEM[36864];
    const int nblk = a.nblk;
    const int tid = threadIdx.x;

    // ---------------- S0: prep (1656 logical blocks) ----------------
    for (int vb = blockIdx.x; vb < 1656; vb += nblk) {
        if (vb < 512) {
            // head cast [4096][300]->[4096][320] bf16 (+ ranges on vb 0)
            const int q = vb;
            if (q == 0 && tid < 128) {
                int b = tid & 63;
                const int* arr = (tid < 64) ? a.bh : a.bt;
                int base = (tid < 64) ? 0 : 128;
                int lo = 0, hi = NTOK;
                while (lo < hi) { int mid = (lo + hi) >> 1; if (arr[mid] < b) lo = mid + 1; else hi = mid; }
                int start = lo;
                lo = 0; hi = NTOK;
                while (lo < hi) { int mid = (lo + hi) >> 1; if (arr[mid] <= b) lo = mid + 1; else hi = mid; }
                a.ranges[base + b] = start;
                a.ranges[base + 64 + b] = lo;
            }
            for (int idx = tid; idx < 8 * 40; idx += 256) {
                int r   = q * 8 + idx / 40;
                int col = (idx % 40) * 8;
                bf16x8 v;
                if (col + 8 <= 300) {
                    float4 f0 = *(const float4*)&a.h_head[(size_t)r * 300 + col];
                    float4 f1 = *(const float4*)&a.h_head[(size_t)r * 300 + col + 4];
                    v[0]=(__bf16)f0.x; v[1]=(__bf16)f0.y; v[2]=(__bf16)f0.z; v[3]=(__bf16)f0.w;
                    v[4]=(__bf16)f1.x; v[5]=(__bf16)f1.y; v[6]=(__bf16)f1.z; v[7]=(__bf16)f1.w;
                } else if (col < 300) {
                    float4 f0 = *(const float4*)&a.h_head[(size_t)r * 300 + col];
                    v[0]=(__bf16)f0.x; v[1]=(__bf16)f0.y; v[2]=(__bf16)f0.z; v[3]=(__bf16)f0.w;
                    v[4]=(__bf16)0.f; v[5]=(__bf16)0.f; v[6]=(__bf16)0.f; v[7]=(__bf16)0.f;
                } else {
                    #pragma unroll
                    for (int j = 0; j < 8; ++j) v[j] = (__bf16)0.f;
                }
                *(bf16x8*)&a.hh_bf[(size_t)r * 320 + col] = v;
            }
        } else if (vb < 1024) {
            // tail cast [4096][512] bf16
            const int q = vb - 512;
            for (int idx = tid; idx < 8 * 64; idx += 256) {
                int r   = q * 8 + (idx >> 6);
                int col = (idx & 63) * 8;
                float4 f0 = *(const float4*)&a.h_tail[(size_t)r * 512 + col];
                float4 f1 = *(const float4*)&a.h_tail[(size_t)r * 512 + col + 4];
                bf16x8 v;
                v[0]=(__bf16)f0.x; v[1]=(__bf16)f0.y; v[2]=(__bf16)f0.z; v[3]=(__bf16)f0.w;
                v[4]=(__bf16)f1.x; v[5]=(__bf16)f1.y; v[6]=(__bf16)f1.z; v[7]=(__bf16)f1.w;
                *(bf16x8*)&a.ht_bf[(size_t)r * 512 + col] = v;
            }
        } else if (vb < 1120) {
            // map_w cast -> [384][512], rows >=300 zero
            const int q = vb - 1024;
            int r   = q * 4 + (tid >> 6);
            int col = (tid & 63) * 8;
            bf16x8 v;
            if (r < 300) {
                float4 f0 = *(const float4*)&a.map_w[(size_t)r * 512 + col];
                float4 f1 = *(const float4*)&a.map_w[(size_t)r * 512 + col + 4];
                v[0]=(__bf16)f0.x; v[1]=(__bf16)f0.y; v[2]=(__bf16)f0.z; v[3]=(__bf16)f0.w;
                v[4]=(__bf16)f1.x; v[5]=(__bf16)f1.y; v[6]=(__bf16)f1.z; v[7]=(__bf16)f1.w;
            } else {
                #pragma unroll
                for (int j = 0; j < 8; ++j) v[j] = (__bf16)0.f;
            }
            *(bf16x8*)&a.mapw_bf[(size_t)r * 512 + col] = v;
        } else if (vb < 1144) {
            // fused bias fb[w][n] = map_b . W[:,n] + b[n]  (24 blocks, parallel)
            __syncthreads();
            float* red = (float*)SMEM;
            const int i  = vb - 1120;
            const int w  = i >> 3;
            const int c8 = i & 7;
            const int n  = c8 * 64 + (tid & 63);
            const int jq = tid >> 6;
            const float* W = a.wsrc[w];
            float s = 0.f;
            for (int j = jq * 128; j < jq * 128 + 128; ++j)
                s += a.map_b[j] * W[(size_t)j * 512 + n];
            red[tid] = s;
            __syncthreads();
            if (tid < 64) {
                float r4 = red[tid] + red[64 + tid] + red[128 + tid] + red[192 + tid]
                         + a.qkvb1[w][c8 * 64 + tid];
                a.fb[w * 512 + c8 * 64 + tid] = r4;
            }
        } else {
            // weight transpose: 8 jobs x 64 tiles
            __syncthreads();
            typedef __bf16 trow[72];
            trow* T = (trow*)SMEM;
            const int i  = vb - 1144;
            const int jz = i >> 6;
            const int q  = i & 63;
            const float* src = a.wsrc[jz];
            __bf16* dst = a.wT[jz];
            const int tk = (q >> 3) * 64;
            const int tn = (q & 7) * 64;
            const int r0 = tid >> 4;
            const int c0 = (tid & 15) * 4;
            #pragma unroll
            for (int ii = 0; ii < 4; ++ii) {
                float4 v = *(const float4*)&src[(size_t)(tk + r0 + ii * 16) * 512 + tn + c0];
                T[r0 + ii * 16][c0 + 0] = (__bf16)v.x;
                T[r0 + ii * 16][c0 + 1] = (__bf16)v.y;
                T[r0 + ii * 16][c0 + 2] = (__bf16)v.z;
                T[r0 + ii * 16][c0 + 3] = (__bf16)v.w;
            }
            __syncthreads();
            const int n  = tid >> 2;
            const int kk = (tid & 3) * 16;
            bf16x8 o0, o1;
            #pragma unroll
            for (int j = 0; j < 8; ++j) { o0[j] = T[kk + j][n]; o1[j] = T[kk + 8 + j][n]; }
            __bf16* dp = dst + (size_t)(tn + n) * 512 + tk + kk;
            *(bf16x8*)dp       = o0;
            *(bf16x8*)(dp + 8) = o1;
        }
    }
    grid_barrier(a.bar + 0, nblk);

    // ---------------- S1: fold GEMMs (36 tiles) ----------------
    for (int vb = blockIdx.x; vb < 36; vb += nblk) {
        const int z  = vb % 3;
        const int t  = vb / 3;
        const int bx = t % 3;
        const int by = t / 3;
        gemm_tile<__bf16>(a.wT[z], a.mapw_bf, nullptr, a.F[z], 512, 320, 320, bx, by, SMEM);
    }
    grid_barrier(a.bar + 16, nblk);

    // ---------------- S2: qkv GEMMs (768 tiles) ----------------
    for (int vb = blockIdx.x; vb < 768; vb += nblk) {
        const int z  = vb >> 7;
        const int r  = vb & 127;
        const int bx = r & 3;
        const int by = r >> 2;
        const __bf16* Aj; const __bf16* Wj; const float* bj; __bf16* Cj; int Kpj;
        if (z < 3) {
            Aj = a.hh_bf; Wj = a.F[z]; bj = a.fb + z * 512;
            Cj = (z == 0) ? a.qh : (z == 1) ? a.kh : a.vh;
            Kpj = 320;
        } else {
            Aj = a.ht_bf; Wj = a.wT[z]; bj = a.b2[z - 3];
            Cj = (z == 3) ? a.qt : (z == 4) ? a.kt : a.vt;
            Kpj = 512;
        }
        gemm_tile<__bf16>(Aj, Wj, bj, Cj, Kpj, HID, HID, bx, by, SMEM);
    }
    grid_barrier(a.bar + 32, nblk);

    // ---------------- S3: attention (1024 blocks) ----------------
    for (int vb = blockIdx.x; vb < 1024; vb += nblk) {
        const int h = vb & 7;
        const int b = (vb >> 3) & 63;
        const int z = vb >> 9;
        attn_block(a, h, b, z, SMEM);
    }
    grid_barrier(a.bar + 48, nblk);

    // ---------------- S4: output projections (256 tiles) ----------------
    for (int vb = blockIdx.x; vb < 256; vb += nblk) {
        const int z  = vb >> 7;
        const int r  = vb & 127;
        const int bx = r & 3;
        const int by = r >> 2;
        const __bf16* Aj = z ? a.ctxt : a.ctxh;
        const __bf16* Wj = z ? a.wT[7] : a.wT[6];
        const float*  bj = z ? a.d2_b : a.d1_b;
        float* Cj = a.out + (size_t)z * NTOK * HID;
        gemm_tile<float>(Aj, Wj, bj, Cj, 512, HID, HID, bx, by, SMEM);
    }
}

// ------------------------------ launcher -----------------------------------
extern "C" void kernel_launch(void* const* d_in, const int* in_sizes, int n_in,
                              void* d_out, int out_size, void* d_ws, size_t ws_size,
                              hipStream_t stream) {
    (void)in_sizes; (void)n_in; (void)out_size; (void)ws_size;

    const size_t SZ = (size_t)NTOK * HID;
    char* ws = (char*)d_ws;
    int* bar      = (int*)ws;                              // 4 counters @ 64B
    int* ranges   = (int*)(ws + 512);                      // 1 KB
    __bf16* hh_bf = (__bf16*)(ws + 2048);                  // [4096][320]
    __bf16* ht_bf = hh_bf + (size_t)NTOK * 320;            // [4096][512]
    __bf16* mapw  = ht_bf + SZ;                            // [384][512]
    __bf16* wT0   = mapw + 384 * 512;                      // 8 x [512][512]
    __bf16* F0    = wT0 + 8 * 512 * 512;                   // 3 x [512][320]
    __bf16* qh    = F0 + 3 * 512 * 320;                    // 8 x [4096][512]
    float*  fb    = (float*)(qh + 8 * SZ);                 // [3][512]

    MegaArgs a;
    a.h_head = (const float*)d_in[0];
    a.h_tail = (const float*)d_in[1];
    a.bh     = (const int*)d_in[2];
    a.bt     = (const int*)d_in[3];
    a.map_w  = (const float*)d_in[4];
    a.map_b  = (const float*)d_in[5];
    // wsrc order: q1,k1,v1,q2,k2,v2,d1,d2 at d_in[6,8,10,12,14,16,18,20]
    for (int i = 0; i < 8; ++i) a.wsrc[i] = (const float*)d_in[6 + 2 * i];
    a.qkvb1[0] = (const float*)d_in[7];    // q1_b
    a.qkvb1[1] = (const float*)d_in[9];    // k1_b
    a.qkvb1[2] = (const float*)d_in[11];   // v1_b
    a.b2[0]    = (const float*)d_in[13];   // q2_b
    a.b2[1]    = (const float*)d_in[15];   // k2_b
    a.b2[2]    = (const float*)d_in[17];   // v2_b
    a.d1_b     = (const float*)d_in[19];
    a.d2_b     = (const float*)d_in[21];

    for (int i = 0; i < 8; ++i) a.wT[i] = wT0 + (size_t)i * 512 * 512;
    a.hh_bf = hh_bf; a.ht_bf = ht_bf; a.mapw_bf = mapw;
    for (int i = 0; i < 3; ++i) a.F[i] = F0 + (size_t)i * 512 * 320;
    a.qh = qh;            a.kh = qh + SZ;       a.vh = qh + 2 * SZ;
    a.qt = qh + 3 * SZ;   a.kt = qh + 4 * SZ;   a.vt = qh + 5 * SZ;
    a.ctxh = qh + 6 * SZ; a.ctxt = qh + 7 * SZ;
    a.fb = fb; a.ranges = ranges;
    a.out = (float*)d_out;
    a.bar = bar;

    // grid sized to guaranteed co-residency (deadlock-free software barrier)
    static int g_nblk = 0;
    if (g_nblk == 0) {
        int dev = 0, ncu = 0, occ = 0;
        hipGetDevice(&dev);
        hipDeviceGetAttribute(&ncu, hipDeviceAttributeMultiprocessorCount, dev);
        hipOccupancyMaxActiveBlocksPerMultiprocessor(&occ, mega, 256, 0);
        if (ncu < 1) ncu = 256;
        if (occ < 1) occ = 1;
        long cap = (long)occ * (long)ncu;
        g_nblk = (int)(cap < 768 ? cap : 768);
    }
    a.nblk = g_nblk;

    hipMemsetAsync(bar, 0, 256, stream);
    mega<<<dim3(g_nblk), dim3(256), 0, stream>>>(a);
}

// Round 3
// 200.564 us; speedup vs baseline: 1.9625x; 1.9625x over previous
//
#include <hip/hip_runtime.h>
#include <hip/hip_bf16.h>
#include <math.h>

// ---------------------------------------------------------------------------
// CrossModalityMultiHeadAttention  (MI355X / gfx950)
// Round 10: revert mega-kernel (software grid barriers cost ~50-80us each:
// profiled MfmaUtil 0.9%, VALUBusy 1.5% -> 330us of barrier stall).
// Back to multi-dispatch, round-8 structure, with the fold GEMM co-scheduled
// inside the qkv-tail dispatch instead of its own serialized 36-block launch:
//   D1: prep casts + ranges + 8 weight transposes + mapw cast + parallel fb
//   D2: flat 420 blocks = fold(36: FqT/FkT/FvT = wT @ mapw^T) + qkv-tail(384)
//   D3: head qkv at Kp=320 using folded weights (3 x 128 tiles)
//   D4: attention (both sides)
//   D5: output projections
// All GEMM/attn inner loops byte-identical to round-7/8 proven code.
// ---------------------------------------------------------------------------

typedef __bf16 bf16x8 __attribute__((ext_vector_type(8)));
typedef float  f32x4  __attribute__((ext_vector_type(4)));

#define HID 512
#define NTOK 4096

#define AS1(p) ((const __attribute__((address_space(1))) void*)(p))
#define AS3(p) ((__attribute__((address_space(3))) void*)(p))

// --------------------- fused prep / transpose / cast -----------------------
// grid (512, 1, 11):
//   z=0 : h_head fp32 -> hh_bf [4096][320] (pad 300..319 = 0) + ranges
//   z=1 : h_tail fp32 -> ht_bf [4096][512]
//   z=2 : q<96    : map_w fp32 -> mapw_bf [384][512] (rows 300..383 = 0)
//         q<120   : parallel fused bias fb[w][n] = map_b . W[:,n] + b[n]
//   z=3..10 : weight transpose W[512][512] fp32 -> WT[512][512] bf16
struct PrepArgs {
    const float* h_head; const float* h_tail;
    const int* bh; const int* bt;
    const float* map_w; const float* map_b;
    const float* qkvw[3]; const float* qkvb[3];
    const float* tsrc[8]; __bf16* tdst[8];
    __bf16* hh_bf; __bf16* ht_bf; __bf16* mapw_bf;
    float* fb;            // [3][512] fp32
    int* ranges;
};

__global__ __launch_bounds__(256) void fused_prep(PrepArgs pa) {
    const int q = blockIdx.x, z = blockIdx.z, tid = threadIdx.x;
    __shared__ __align__(16) __bf16 T[64][72];

    if (z == 0) {
        if (q == 0 && tid < 128) {
            int b = tid & 63;
            const int* arr = (tid < 64) ? pa.bh : pa.bt;
            int base = (tid < 64) ? 0 : 128;
            int lo = 0, hi = NTOK;
            while (lo < hi) { int mid = (lo + hi) >> 1; if (arr[mid] < b) lo = mid + 1; else hi = mid; }
            int start = lo;
            lo = 0; hi = NTOK;
            while (lo < hi) { int mid = (lo + hi) >> 1; if (arr[mid] <= b) lo = mid + 1; else hi = mid; }
            pa.ranges[base + b] = start;
            pa.ranges[base + 64 + b] = lo;
        }
        for (int idx = tid; idx < 8 * 40; idx += 256) {
            int r   = q * 8 + idx / 40;
            int col = (idx % 40) * 8;
            bf16x8 v;
            if (col + 8 <= 300) {
                float4 f0 = *(const float4*)&pa.h_head[(size_t)r * 300 + col];
                float4 f1 = *(const float4*)&pa.h_head[(size_t)r * 300 + col + 4];
                v[0]=(__bf16)f0.x; v[1]=(__bf16)f0.y; v[2]=(__bf16)f0.z; v[3]=(__bf16)f0.w;
                v[4]=(__bf16)f1.x; v[5]=(__bf16)f1.y; v[6]=(__bf16)f1.z; v[7]=(__bf16)f1.w;
            } else if (col < 300) {  // col == 296: 4 valid + 4 pad
                float4 f0 = *(const float4*)&pa.h_head[(size_t)r * 300 + col];
                v[0]=(__bf16)f0.x; v[1]=(__bf16)f0.y; v[2]=(__bf16)f0.z; v[3]=(__bf16)f0.w;
                v[4]=(__bf16)0.f; v[5]=(__bf16)0.f; v[6]=(__bf16)0.f; v[7]=(__bf16)0.f;
            } else {
                #pragma unroll
                for (int j = 0; j < 8; ++j) v[j] = (__bf16)0.f;
            }
            *(bf16x8*)&pa.hh_bf[(size_t)r * 320 + col] = v;
        }
    } else if (z == 1) {
        for (int idx = tid; idx < 8 * 64; idx += 256) {
            int r   = q * 8 + (idx >> 6);
            int col = (idx & 63) * 8;
            float4 f0 = *(const float4*)&pa.h_tail[(size_t)r * 512 + col];
            float4 f1 = *(const float4*)&pa.h_tail[(size_t)r * 512 + col + 4];
            bf16x8 v;
            v[0]=(__bf16)f0.x; v[1]=(__bf16)f0.y; v[2]=(__bf16)f0.z; v[3]=(__bf16)f0.w;
            v[4]=(__bf16)f1.x; v[5]=(__bf16)f1.y; v[6]=(__bf16)f1.z; v[7]=(__bf16)f1.w;
            *(bf16x8*)&pa.ht_bf[(size_t)r * 512 + col] = v;
        }
    } else if (z == 2) {
        if (q < 96) {
            // map_w bf16 cast, 4 rows/block, zero-pad rows >= 300
            int r   = q * 4 + (tid >> 6);
            int col = (tid & 63) * 8;
            bf16x8 v;
            if (r < 300) {
                float4 f0 = *(const float4*)&pa.map_w[(size_t)r * 512 + col];
                float4 f1 = *(const float4*)&pa.map_w[(size_t)r * 512 + col + 4];
                v[0]=(__bf16)f0.x; v[1]=(__bf16)f0.y; v[2]=(__bf16)f0.z; v[3]=(__bf16)f0.w;
                v[4]=(__bf16)f1.x; v[5]=(__bf16)f1.y; v[6]=(__bf16)f1.z; v[7]=(__bf16)f1.w;
            } else {
                #pragma unroll
                for (int j = 0; j < 8; ++j) v[j] = (__bf16)0.f;
            }
            *(bf16x8*)&pa.mapw_bf[(size_t)r * 512 + col] = v;
        } else if (q < 120) {
            // parallel fused bias (24 blocks): fb[w][n] = map_b . W[:,n] + b[n]
            float* red = (float*)T;
            const int i  = q - 96;
            const int w  = i >> 3;
            const int c8 = i & 7;
            const int n  = c8 * 64 + (tid & 63);
            const int jq = tid >> 6;
            const float* W = pa.qkvw[w];
            float s = 0.f;
            for (int j = jq * 128; j < jq * 128 + 128; ++j)
                s += pa.map_b[j] * W[(size_t)j * 512 + n];
            red[tid] = s;
            __syncthreads();
            if (tid < 64) {
                float r4 = red[tid] + red[64 + tid] + red[128 + tid] + red[192 + tid]
                         + pa.qkvb[w][c8 * 64 + tid];
                pa.fb[w * 512 + c8 * 64 + tid] = r4;
            }
        }
    } else {
        if (q >= 64) return;
        const int jz = z - 3;
        const float* src = pa.tsrc[jz];
        __bf16* dst = pa.tdst[jz];
        const int tk = (q >> 3) * 64;
        const int tn = (q & 7) * 64;
        const int r0 = tid >> 4;
        const int c0 = (tid & 15) * 4;
        #pragma unroll
        for (int i = 0; i < 4; ++i) {
            float4 v = *(const float4*)&src[(size_t)(tk + r0 + i * 16) * 512 + tn + c0];
            T[r0 + i * 16][c0 + 0] = (__bf16)v.x;
            T[r0 + i * 16][c0 + 1] = (__bf16)v.y;
            T[r0 + i * 16][c0 + 2] = (__bf16)v.z;
            T[r0 + i * 16][c0 + 3] = (__bf16)v.w;
        }
        __syncthreads();
        const int n  = tid >> 2;
        const int kk = (tid & 3) * 16;
        bf16x8 o0, o1;
        #pragma unroll
        for (int j = 0; j < 8; ++j) { o0[j] = T[kk + j][n]; o1[j] = T[kk + 8 + j][n]; }
        __bf16* dp = dst + (size_t)(tn + n) * 512 + tk + kk;
        *(bf16x8*)dp       = o0;
        *(bf16x8*)(dp + 8) = o1;
    }
}

// ------------------------------ GEMM body ----------------------------------
// C[row][col] = sum_k A[row][k]*W[col][k] + bias[col].
// Byte-identical main loop to round 7 (double-buffered global_load_lds +
// XOR k-chunk swizzle); epilogue parameterized by ldC/Ncol.
template <typename TC>
__device__ __forceinline__ void gemm_body(
    const __bf16* __restrict__ A, const __bf16* __restrict__ W,
    const float* __restrict__ bias, TC* __restrict__ C,
    int Kp, int ldC, int Ncol, int bx, int by,
    __bf16* As, __bf16* Bs)
{
    const int tid  = threadIdx.x;
    const int wave = tid >> 6;
    const int lane = tid & 63;
    const int quad = lane >> 4;
    const int l16  = lane & 15;
    const int wy   = wave >> 1;
    const int wx   = wave & 1;
    const int rowBase = by * 128;
    const int colBase = bx * 128;

    const int s_row = tid >> 2;
    const int s_kc  = ((tid & 3) ^ ((s_row >> 1) & 3)) * 8;

    const __bf16* gA = A + (size_t)(rowBase + s_row) * Kp + s_kc;
    const __bf16* gB = W + (size_t)(colBase + s_row) * Kp + s_kc;
    const int waveOff = wave * 512;

    f32x4 acc[4][4] = {};
    const int nk = Kp >> 5;

    __builtin_amdgcn_global_load_lds(AS1(gA),                   AS3(&As[waveOff]),        16, 0, 0);
    __builtin_amdgcn_global_load_lds(AS1(gA + (size_t)64 * Kp), AS3(&As[2048 + waveOff]), 16, 0, 0);
    __builtin_amdgcn_global_load_lds(AS1(gB),                   AS3(&Bs[waveOff]),        16, 0, 0);
    __builtin_amdgcn_global_load_lds(AS1(gB + (size_t)64 * Kp), AS3(&Bs[2048 + waveOff]), 16, 0, 0);

    for (int i = 0; i < nk; ++i) {
        const int cur = i & 1;
        __syncthreads();   // drains tile i's loads; prev reads of buf[cur^1] done

        if (i + 1 < nk) {  // issue tile i+1 into the other buffer
            const int kt = (i + 1) * 32;
            const int nx = cur ^ 1;
            __builtin_amdgcn_global_load_lds(AS1(gA + kt),                   AS3(&As[nx * 4096 + waveOff]),        16, 0, 0);
            __builtin_amdgcn_global_load_lds(AS1(gA + kt + (size_t)64 * Kp), AS3(&As[nx * 4096 + 2048 + waveOff]), 16, 0, 0);
            __builtin_amdgcn_global_load_lds(AS1(gB + kt),                   AS3(&Bs[nx * 4096 + waveOff]),        16, 0, 0);
            __builtin_amdgcn_global_load_lds(AS1(gB + kt + (size_t)64 * Kp), AS3(&Bs[nx * 4096 + 2048 + waveOff]), 16, 0, 0);
        }

        bf16x8 ar[4], br[4];
        #pragma unroll
        for (int ii = 0; ii < 4; ++ii) {
            const int ra = wy * 64 + ii * 16 + l16;
            ar[ii] = *(const bf16x8*)&As[cur * 4096 + ra * 32 + ((quad ^ ((ra >> 1) & 3)) << 3)];
        }
        #pragma unroll
        for (int jj = 0; jj < 4; ++jj) {
            const int rb = wx * 64 + jj * 16 + l16;
            br[jj] = *(const bf16x8*)&Bs[cur * 4096 + rb * 32 + ((quad ^ ((rb >> 1) & 3)) << 3)];
        }
        #pragma unroll
        for (int ii = 0; ii < 4; ++ii)
            #pragma unroll
            for (int jj = 0; jj < 4; ++jj)
                acc[ii][jj] = __builtin_amdgcn_mfma_f32_16x16x32_bf16(ar[ii], br[jj], acc[ii][jj], 0, 0, 0);
    }

    // epilogue: C/D layout col=l16, row=quad*4+reg
    #pragma unroll
    for (int jj = 0; jj < 4; ++jj) {
        int col = colBase + wx * 64 + jj * 16 + l16;
        if (col < Ncol) {
            float bv = bias ? bias[col] : 0.f;
            #pragma unroll
            for (int ii = 0; ii < 4; ++ii) {
                #pragma unroll
                for (int r = 0; r < 4; ++r) {
                    int row = rowBase + wy * 64 + ii * 16 + quad * 4 + r;
                    C[(size_t)row * ldC + col] = (TC)(acc[ii][jj][r] + bv);
                }
            }
        }
    }
}

// -------- z-indexed GEMM wrapper (D3 qkv-head, D5 out-proj) --------
struct GemmJobs {
    const __bf16* A[3];
    const __bf16* W[3];
    const float*  bias[3];
    void*         C[3];
    int           Kp[3];
};

template <typename TC>
__global__ __launch_bounds__(256) void gemm128(GemmJobs jobs) {
    __shared__ __align__(16) __bf16 As[2][4096];
    __shared__ __align__(16) __bf16 Bs[2][4096];
    const int z = blockIdx.z;
    gemm_body<TC>(jobs.A[z], jobs.W[z], jobs.bias[z], (TC*)jobs.C[z],
                  jobs.Kp[z], HID, HID, blockIdx.x, blockIdx.y,
                  &As[0][0], &Bs[0][0]);
}

// -------- D2: flat fold(36) + qkv-tail(384) wrapper --------
struct D2Args {
    const __bf16* wT1[3];   // q1T,k1T,v1T
    const __bf16* mapw;     // [384][512]
    __bf16*       F[3];     // [512][320]
    const __bf16* ht;       // [4096][512]
    const __bf16* w2T[3];   // q2T,k2T,v2T
    const float*  b2[3];
    __bf16*       out2[3];  // qt,kt,vt
};

__global__ __launch_bounds__(256) void gemm_d2(D2Args d) {
    __shared__ __align__(16) __bf16 As[2][4096];
    __shared__ __align__(16) __bf16 Bs[2][4096];
    const int vb = blockIdx.x;
    if (vb < 36) {
        // fold: F[f][n][k] = sum_j wT1[f][n][j] * mapw[k][j]
        const int f = vb / 12, t = vb % 12;
        gemm_body<__bf16>(d.wT1[f], d.mapw, nullptr, d.F[f],
                          512, 320, 320, t % 3, t / 3, &As[0][0], &Bs[0][0]);
    } else {
        const int u = vb - 36;
        const int w = u >> 7, t = u & 127;
        gemm_body<__bf16>(d.ht, d.w2T[w], d.b2[w], d.out2[w],
                          512, HID, HID, t & 3, t >> 2, &As[0][0], &Bs[0][0]);
    }
}

// ------------------------- MFMA flash attention ----------------------------
// grid = (head 8, batch 64, side 2). side 0: head-q x tail-k; side 1: swap.
__global__ __launch_bounds__(256) void attn_mfma(
    const __bf16* __restrict__ Q0, const __bf16* __restrict__ K0,
    const __bf16* __restrict__ Vr0, const __bf16* __restrict__ Vc0,
    const __bf16* __restrict__ Q1, const __bf16* __restrict__ K1,
    const __bf16* __restrict__ Vr1, const __bf16* __restrict__ Vc1,
    const int* __restrict__ ranges,
    __bf16* __restrict__ O0, __bf16* __restrict__ O1,
    int Nq, int Nk)
{
    __shared__ __align__(16) __bf16 Qs[64][72];
    __shared__ __align__(16) __bf16 Ks[64][72];
    __shared__ __align__(16) __bf16 Vt[64][72];   // [dim][key]
    __shared__ __align__(16) __bf16 Ps[64][72];   // [query][key]

    const int z = blockIdx.z;
    const __bf16* Q    = z ? Q1 : Q0;
    const __bf16* Kg   = z ? K1 : K0;
    const __bf16* Vres = z ? Vr1 : Vr0;
    const __bf16* Vctx = z ? Vc1 : Vc0;
    __bf16* Out        = z ? O1 : O0;
    const int* qstart  = z ? ranges + 128 : ranges;
    const int* qend    = z ? ranges + 192 : ranges + 64;
    const int* kstart  = z ? ranges       : ranges + 128;
    const int* kend    = z ? ranges + 64  : ranges + 192;

    const int h = blockIdx.x, b = blockIdx.y;
    const int qs = qstart[b], qe = qend[b];
    const int ts = kstart[b], te = kend[b];
    const int nq = qe - qs, nk = te - ts;
    if (nq <= 0) return;

    const int tid  = threadIdx.x;
    const int wave = tid >> 6;
    const int lane = tid & 63;
    const int quad = lane >> 4;
    const int l16  = lane & 15;
    const int srow = tid >> 2;
    const int scol = (tid & 3) * 16;

    if (nk <= 0) {
        float* meanv = (float*)Qs;
        if (tid < 64) {
            float s = 0.f;
            for (int m = 0; m < Nk; ++m)
                s += (float)Vctx[(size_t)m * HID + h * 64 + tid];
            meanv[tid] = s / (float)Nk;
        }
        __syncthreads();
        int d = tid & 63;
        for (int r = qs + (tid >> 6); r < qe; r += 4) {
            size_t off = (size_t)r * HID + h * 64 + d;
            Out[off] = (__bf16)((float)Vres[off] + meanv[d]);
        }
        return;
    }

    for (int qc = 0; qc < nq; qc += 64) {
        __syncthreads();
        {
            int qg = min(qs + qc + srow, Nq - 1);
            const __bf16* src = Q + (size_t)qg * HID + h * 64 + scol;
            *(bf16x8*)&Qs[srow][scol]     = *(const bf16x8*)src;
            *(bf16x8*)&Qs[srow][scol + 8] = *(const bf16x8*)(src + 8);
        }
        __syncthreads();
        bf16x8 aq0 = *(const bf16x8*)&Qs[wave * 16 + l16][quad * 8];
        bf16x8 aq1 = *(const bf16x8*)&Qs[wave * 16 + l16][32 + quad * 8];

        f32x4 O[4] = {};
        float Mx[4], L[4];
        #pragma unroll
        for (int r = 0; r < 4; ++r) { Mx[r] = -__builtin_inff(); L[r] = 0.f; }

        for (int kc = 0; kc < nk; kc += 64) {
            __syncthreads();
            {
                int kg = min(ts + kc + srow, Nk - 1);
                const __bf16* ksrc = Kg + (size_t)kg * HID + h * 64 + scol;
                *(bf16x8*)&Ks[srow][scol]     = *(const bf16x8*)ksrc;
                *(bf16x8*)&Ks[srow][scol + 8] = *(const bf16x8*)(ksrc + 8);
                const __bf16* vsrc = Vctx + (size_t)kg * HID + h * 64 + scol;
                bf16x8 v0 = *(const bf16x8*)vsrc;
                bf16x8 v1 = *(const bf16x8*)(vsrc + 8);
                #pragma unroll
                for (int j = 0; j < 8; ++j) {
                    Vt[scol + j][srow]     = v0[j];
                    Vt[scol + 8 + j][srow] = v1[j];
                }
            }
            __syncthreads();

            f32x4 S[4] = {};
            #pragma unroll
            for (int c = 0; c < 4; ++c) {
                bf16x8 bk0 = *(const bf16x8*)&Ks[c * 16 + l16][quad * 8];
                bf16x8 bk1 = *(const bf16x8*)&Ks[c * 16 + l16][32 + quad * 8];
                S[c] = __builtin_amdgcn_mfma_f32_16x16x32_bf16(aq0, bk0, S[c], 0, 0, 0);
                S[c] = __builtin_amdgcn_mfma_f32_16x16x32_bf16(aq1, bk1, S[c], 0, 0, 0);
            }

            #pragma unroll
            for (int c = 0; c < 4; ++c) {
                bool valid = (ts + kc + c * 16 + l16) < te;
                #pragma unroll
                for (int r = 0; r < 4; ++r)
                    S[c][r] = valid ? S[c][r] * 0.125f : -__builtin_inff();
            }

            float cm[4], ps[4], alpha[4];
            #pragma unroll
            for (int r = 0; r < 4; ++r) {
                float v = fmaxf(fmaxf(S[0][r], S[1][r]), fmaxf(S[2][r], S[3][r]));
                v = fmaxf(v, __shfl_xor(v, 1, 64));
                v = fmaxf(v, __shfl_xor(v, 2, 64));
                v = fmaxf(v, __shfl_xor(v, 4, 64));
                v = fmaxf(v, __shfl_xor(v, 8, 64));
                cm[r] = v;
            }
            #pragma unroll
            for (int r = 0; r < 4; ++r) {
                float nM = fmaxf(Mx[r], cm[r]);
                alpha[r] = __expf(Mx[r] - nM);
                Mx[r] = nM;
                ps[r] = 0.f;
            }
            #pragma unroll
            for (int c = 0; c < 4; ++c)
                #pragma unroll
                for (int r = 0; r < 4; ++r) {
                    float p = __expf(S[c][r] - Mx[r]);
                    S[c][r] = p;
                    ps[r] += p;
                }
            #pragma unroll
            for (int r = 0; r < 4; ++r) {
                float v = ps[r];
                v += __shfl_xor(v, 1, 64);
                v += __shfl_xor(v, 2, 64);
                v += __shfl_xor(v, 4, 64);
                v += __shfl_xor(v, 8, 64);
                L[r] = L[r] * alpha[r] + v;
            }
            #pragma unroll
            for (int c = 0; c < 4; ++c)
                #pragma unroll
                for (int r = 0; r < 4; ++r)
                    O[c][r] *= alpha[r];

            #pragma unroll
            for (int c = 0; c < 4; ++c)
                #pragma unroll
                for (int r = 0; r < 4; ++r)
                    Ps[wave * 16 + quad * 4 + r][c * 16 + l16] = (__bf16)S[c][r];
            __syncthreads();

            bf16x8 ap0 = *(const bf16x8*)&Ps[wave * 16 + l16][quad * 8];
            bf16x8 ap1 = *(const bf16x8*)&Ps[wave * 16 + l16][32 + quad * 8];
            #pragma unroll
            for (int c = 0; c < 4; ++c) {
                bf16x8 bv0 = *(const bf16x8*)&Vt[c * 16 + l16][quad * 8];
                bf16x8 bv1 = *(const bf16x8*)&Vt[c * 16 + l16][32 + quad * 8];
                O[c] = __builtin_amdgcn_mfma_f32_16x16x32_bf16(ap0, bv0, O[c], 0, 0, 0);
                O[c] = __builtin_amdgcn_mfma_f32_16x16x32_bf16(ap1, bv1, O[c], 0, 0, 0);
            }
        }

        #pragma unroll
        for (int c = 0; c < 4; ++c) {
            int d = h * 64 + c * 16 + l16;
            #pragma unroll
            for (int r = 0; r < 4; ++r) {
                int qrow = qs + qc + wave * 16 + quad * 4 + r;
                if (qrow < qe) {
                    size_t off = (size_t)qrow * HID + d;
                    Out[off] = (__bf16)((float)Vres[off] + O[c][r] / L[r]);
                }
            }
        }
    }
}

// ------------------------------ launcher -----------------------------------
extern "C" void kernel_launch(void* const* d_in, const int* in_sizes, int n_in,
                              void* d_out, int out_size, void* d_ws, size_t ws_size,
                              hipStream_t stream) {
    (void)in_sizes; (void)n_in; (void)out_size; (void)ws_size;

    const float* h_head = (const float*)d_in[0];
    const float* h_tail = (const float*)d_in[1];
    const int* batch_head = (const int*)d_in[2];
    const int* batch_tail = (const int*)d_in[3];
    const float* map_w = (const float*)d_in[4];
    const float* map_b = (const float*)d_in[5];
    const float* q1_w = (const float*)d_in[6];
    const float* q1_b = (const float*)d_in[7];
    const float* k1_w = (const float*)d_in[8];
    const float* k1_b = (const float*)d_in[9];
    const float* v1_w = (const float*)d_in[10];
    const float* v1_b = (const float*)d_in[11];
    const float* q2_w = (const float*)d_in[12];
    const float* q2_b = (const float*)d_in[13];
    const float* k2_w = (const float*)d_in[14];
    const float* k2_b = (const float*)d_in[15];
    const float* v2_w = (const float*)d_in[16];
    const float* v2_b = (const float*)d_in[17];
    const float* d1_w = (const float*)d_in[18];
    const float* d1_b = (const float*)d_in[19];
    const float* d2_w = (const float*)d_in[20];
    const float* d2_b = (const float*)d_in[21];

    float* out = (float*)d_out;

    const size_t SZ = (size_t)NTOK * HID;
    char* ws = (char*)d_ws;
    int* ranges   = (int*)ws;                            // 1 KB
    __bf16* hh_bf = (__bf16*)(ws + 1024);                // [4096][320]
    __bf16* ht_bf = hh_bf + (size_t)NTOK * 320;          // [4096][512]
    __bf16* mapw_bf = ht_bf + SZ;                        // [384][512]
    __bf16* q1T  = mapw_bf + 384 * 512;                  // [512][512] each
    __bf16* k1T  = q1T + 512 * 512;
    __bf16* v1T  = k1T + 512 * 512;
    __bf16* q2T  = v1T + 512 * 512;
    __bf16* k2T  = q2T + 512 * 512;
    __bf16* v2T  = k2T + 512 * 512;
    __bf16* d1T  = v2T + 512 * 512;
    __bf16* d2T  = d1T + 512 * 512;
    __bf16* FqT  = d2T + 512 * 512;                      // [512][320] each
    __bf16* FkT  = FqT + 512 * 320;
    __bf16* FvT  = FkT + 512 * 320;
    __bf16* qh   = FvT + 512 * 320;                      // [4096][512] each
    __bf16* kh   = qh  + SZ;
    __bf16* vh   = kh  + SZ;
    __bf16* qt   = vh  + SZ;
    __bf16* kt   = qt  + SZ;
    __bf16* vt   = kt  + SZ;
    __bf16* ctxh = vt  + SZ;
    __bf16* ctxt = ctxh + SZ;
    float*  fb   = (float*)(ctxt + SZ);                  // [3][512] fp32

    // D1: prep + all transposes + map cast + parallel bias fold
    PrepArgs pa;
    pa.h_head = h_head; pa.h_tail = h_tail;
    pa.bh = batch_head; pa.bt = batch_tail;
    pa.map_w = map_w; pa.map_b = map_b;
    pa.qkvw[0] = q1_w; pa.qkvw[1] = k1_w; pa.qkvw[2] = v1_w;
    pa.qkvb[0] = q1_b; pa.qkvb[1] = k1_b; pa.qkvb[2] = v1_b;
    const float* wsrc[8] = {q1_w, k1_w, v1_w, q2_w, k2_w, v2_w, d1_w, d2_w};
    __bf16* wdst[8] = {q1T, k1T, v1T, q2T, k2T, v2T, d1T, d2T};
    for (int i = 0; i < 8; ++i) { pa.tsrc[i] = wsrc[i]; pa.tdst[i] = wdst[i]; }
    pa.hh_bf = hh_bf; pa.ht_bf = ht_bf; pa.mapw_bf = mapw_bf;
    pa.fb = fb; pa.ranges = ranges;
    fused_prep<<<dim3(512, 1, 11), dim3(256), 0, stream>>>(pa);

    // D2: fold (36 tiles, first) + qkv-tail (384 tiles) in one flat dispatch
    {
        D2Args d;
        d.wT1[0] = q1T; d.wT1[1] = k1T; d.wT1[2] = v1T;
        d.mapw = mapw_bf;
        d.F[0] = FqT; d.F[1] = FkT; d.F[2] = FvT;
        d.ht = ht_bf;
        d.w2T[0] = q2T; d.w2T[1] = k2T; d.w2T[2] = v2T;
        d.b2[0] = q2_b; d.b2[1] = k2_b; d.b2[2] = v2_b;
        d.out2[0] = qt; d.out2[1] = kt; d.out2[2] = vt;
        gemm_d2<<<dim3(420, 1, 1), dim3(256), 0, stream>>>(d);
    }

    // D3: head qkv at Kp=320 with folded weights
    {
        GemmJobs j;
        j.A[0] = hh_bf; j.W[0] = FqT; j.bias[0] = fb;        j.C[0] = qh; j.Kp[0] = 320;
        j.A[1] = hh_bf; j.W[1] = FkT; j.bias[1] = fb + 512;  j.C[1] = kh; j.Kp[1] = 320;
        j.A[2] = hh_bf; j.W[2] = FvT; j.bias[2] = fb + 1024; j.C[2] = vh; j.Kp[2] = 320;
        gemm128<__bf16><<<dim3(4, 32, 3), dim3(256), 0, stream>>>(j);
    }

    // D4: attention (both sides, one dispatch)
    attn_mfma<<<dim3(8, 64, 2), dim3(256), 0, stream>>>(
        qh, kt, vh, vt,
        qt, kh, vt, vh,
        ranges, ctxh, ctxt, NTOK, NTOK);

    // D5: output projections (fp32 into d_out)
    {
        GemmJobs j;
        j.A[0] = ctxh; j.W[0] = d1T; j.bias[0] = d1_b; j.C[0] = out;      j.Kp[0] = 512;
        j.A[1] = ctxt; j.W[1] = d2T; j.bias[1] = d2_b; j.C[1] = out + SZ; j.Kp[1] = 512;
        j.A[2] = ctxt; j.W[2] = d2T; j.bias[2] = d2_b; j.C[2] = out + SZ; j.Kp[2] = 512;
        gemm128<float><<<dim3(4, 32, 2), dim3(256), 0, stream>>>(j);
    }
}

// Round 4
// 198.312 us; speedup vs baseline: 1.9848x; 1.0114x over previous
//
#include <hip/hip_runtime.h>
#include <hip/hip_bf16.h>
#include <math.h>

// ---------------------------------------------------------------------------
// CrossModalityMultiHeadAttention  (MI355X / gfx950)
// Round 11: DEPTH-4 dispatch graph. R9's mega proved total work ~60us; the
// rest is fixed harness tax + per-boundary cost. R8/R10's fold never cut
// depth (fold sat in its own level). Now the fold GEMM reads fp32 weights
// DIRECTLY (custom staging: transposed-coalesced A + natural B, cast in
// regs, swizzled LDS writes matching the proven fragment layout), so it
// lives in D1 alongside the other independent prep jobs:
//   D1: act casts + ranges + fb + transposes(q2,k2,v2,d1,d2) + fold(Fq,Fk,Fv)
//   D2: ALL 6 qkv GEMMs (head: Kp=320 w/ F+fb; tail: Kp=512)
//   D3: attention (both sides)
//   D4: output projections
// q1T/k1T/v1T/mapw_bf eliminated. GEMM/attn inner loops byte-identical to
// the proven round-7 code.
// ---------------------------------------------------------------------------

typedef __bf16 bf16x8 __attribute__((ext_vector_type(8)));
typedef float  f32x4  __attribute__((ext_vector_type(4)));

#define HID 512
#define NTOK 4096

#define AS1(p) ((const __attribute__((address_space(1))) void*)(p))
#define AS3(p) ((__attribute__((address_space(3))) void*)(p))

// ------------------------------ fold tile ----------------------------------
// F[n][k] = sum_j Wf[j][n] * Mw[k][j]   (n<512, k<320 out of 384-tile, j<512)
// A-operand staged TRANSPOSED from fp32 Wf (coalesced: each thread reads 16
// consecutive n of one j-row, then 16 scattered ds_write_b16 into the
// swizzled [128][32] layout). B-operand staged natural from fp32 Mw (rows
// k>=300 zeroed), reg-cast, linear LDS write (same slot map as
// global_load_lds dest). Fragment reads + MFMA identical to gemm_body.
__device__ __forceinline__ void fold_tile(
    const float* __restrict__ Wf,   // [512][512] fp32
    const float* __restrict__ Mw,   // [300][512] fp32
    __bf16* __restrict__ F,         // [512][320] bf16 out
    int bx, int by, char* SMEM)
{
    __bf16* As = (__bf16*)SMEM;            // [128][32]
    __bf16* Bs = (__bf16*)(SMEM + 8192);   // [128][32]

    const int tid  = threadIdx.x;
    const int wave = tid >> 6;
    const int lane = tid & 63;
    const int quad = lane >> 4;
    const int l16  = lane & 15;
    const int wy   = wave >> 1;
    const int wx   = wave & 1;
    const int rowBase = by * 128;   // n
    const int colBase = bx * 128;   // k

    const int s_row = tid >> 2;
    const int s_gc  = (tid & 3) ^ ((s_row >> 1) & 3);   // global j-chunk
    const int a_jj  = tid >> 3;          // 0..31  (j within step)
    const int a_c16 = (tid & 7) * 16;    // n-offset within tile
    const int a_cp  = a_jj >> 3;         // chunk of j
    const int a_sub = a_jj & 7;

    f32x4 acc[4][4] = {};

    for (int i = 0; i < 16; ++i) {
        const int j0 = i * 32;
        __syncthreads();
        // ---- B: Mw rows k (natural), linear LDS slot, swizzled source chunk
        #pragma unroll
        for (int h = 0; h < 2; ++h) {
            int r = s_row + h * 64;
            int k = colBase + r;
            bf16x8 v;
            if (k < 300) {
                const float* p = &Mw[(size_t)k * 512 + j0 + s_gc * 8];
                float4 f0 = *(const float4*)p;
                float4 f1 = *(const float4*)(p + 4);
                v[0]=(__bf16)f0.x; v[1]=(__bf16)f0.y; v[2]=(__bf16)f0.z; v[3]=(__bf16)f0.w;
                v[4]=(__bf16)f1.x; v[5]=(__bf16)f1.y; v[6]=(__bf16)f1.z; v[7]=(__bf16)f1.w;
            } else {
                #pragma unroll
                for (int u = 0; u < 8; ++u) v[u] = (__bf16)0.f;
            }
            *(bf16x8*)&Bs[h * 2048 + tid * 8] = v;
        }
        // ---- A: transposed read Wf[j0+a_jj][rowBase+a_c16 .. +16)
        {
            const float* p = &Wf[(size_t)(j0 + a_jj) * 512 + rowBase + a_c16];
            float4 f0 = *(const float4*)p;
            float4 f1 = *(const float4*)(p + 4);
            float4 f2 = *(const float4*)(p + 8);
            float4 f3 = *(const float4*)(p + 12);
            float vals[16] = {f0.x,f0.y,f0.z,f0.w, f1.x,f1.y,f1.z,f1.w,
                              f2.x,f2.y,f2.z,f2.w, f3.x,f3.y,f3.z,f3.w};
            #pragma unroll
            for (int u = 0; u < 16; ++u) {
                int r  = a_c16 + u;
                int cp = a_cp ^ ((r >> 1) & 3);
                As[r * 32 + cp * 8 + a_sub] = (__bf16)vals[u];
            }
        }
        __syncthreads();

        bf16x8 ar[4], br[4];
        #pragma unroll
        for (int ii = 0; ii < 4; ++ii) {
            const int ra = wy * 64 + ii * 16 + l16;
            ar[ii] = *(const bf16x8*)&As[ra * 32 + ((quad ^ ((ra >> 1) & 3)) << 3)];
        }
        #pragma unroll
        for (int jj = 0; jj < 4; ++jj) {
            const int rb = wx * 64 + jj * 16 + l16;
            br[jj] = *(const bf16x8*)&Bs[rb * 32 + ((quad ^ ((rb >> 1) & 3)) << 3)];
        }
        #pragma unroll
        for (int ii = 0; ii < 4; ++ii)
            #pragma unroll
            for (int jj = 0; jj < 4; ++jj)
                acc[ii][jj] = __builtin_amdgcn_mfma_f32_16x16x32_bf16(ar[ii], br[jj], acc[ii][jj], 0, 0, 0);
    }

    // epilogue: F[n][k], ldC=320, mask k<320
    #pragma unroll
    for (int jj = 0; jj < 4; ++jj) {
        int col = colBase + wx * 64 + jj * 16 + l16;
        if (col < 320) {
            #pragma unroll
            for (int ii = 0; ii < 4; ++ii) {
                #pragma unroll
                for (int r = 0; r < 4; ++r) {
                    int row = rowBase + wy * 64 + ii * 16 + quad * 4 + r;
                    F[(size_t)row * 320 + col] = (__bf16)acc[ii][jj][r];
                }
            }
        }
    }
}

// --------------------- fused prep (depth-4 leaf work) ----------------------
// grid (512, 1, 9):
//   z=0 : h_head fp32 -> hh_bf [4096][320] (pad 300..319 = 0) + ranges
//   z=1 : h_tail fp32 -> ht_bf [4096][512]
//   z=2 : q<24 : parallel fused bias fb[w][n] = map_b . W[:,n] + b[n]
//   z=3 : q<36 : fold tiles (f = q/12, tile = q%12)
//   z=4..8 : weight transpose (q2,k2,v2,d1,d2), q<64 each
struct PrepArgs {
    const float* h_head; const float* h_tail;
    const int* bh; const int* bt;
    const float* map_w; const float* map_b;
    const float* qkvw[3]; const float* qkvb[3];   // q1,k1,v1 fp32 + biases
    const float* tsrc[5]; __bf16* tdst[5];        // q2,k2,v2,d1,d2
    __bf16* hh_bf; __bf16* ht_bf;
    __bf16* F[3];
    float* fb;            // [3][512] fp32
    int* ranges;
};

__global__ __launch_bounds__(256) void fused_prep(PrepArgs pa) {
    const int q = blockIdx.x, z = blockIdx.z, tid = threadIdx.x;
    __shared__ __align__(16) char SMEM[32768];

    if (z == 0) {
        if (q == 0 && tid < 128) {
            int b = tid & 63;
            const int* arr = (tid < 64) ? pa.bh : pa.bt;
            int base = (tid < 64) ? 0 : 128;
            int lo = 0, hi = NTOK;
            while (lo < hi) { int mid = (lo + hi) >> 1; if (arr[mid] < b) lo = mid + 1; else hi = mid; }
            int start = lo;
            lo = 0; hi = NTOK;
            while (lo < hi) { int mid = (lo + hi) >> 1; if (arr[mid] <= b) lo = mid + 1; else hi = mid; }
            pa.ranges[base + b] = start;
            pa.ranges[base + 64 + b] = lo;
        }
        for (int idx = tid; idx < 8 * 40; idx += 256) {
            int r   = q * 8 + idx / 40;
            int col = (idx % 40) * 8;
            bf16x8 v;
            if (col + 8 <= 300) {
                float4 f0 = *(const float4*)&pa.h_head[(size_t)r * 300 + col];
                float4 f1 = *(const float4*)&pa.h_head[(size_t)r * 300 + col + 4];
                v[0]=(__bf16)f0.x; v[1]=(__bf16)f0.y; v[2]=(__bf16)f0.z; v[3]=(__bf16)f0.w;
                v[4]=(__bf16)f1.x; v[5]=(__bf16)f1.y; v[6]=(__bf16)f1.z; v[7]=(__bf16)f1.w;
            } else if (col < 300) {  // col == 296: 4 valid + 4 pad
                float4 f0 = *(const float4*)&pa.h_head[(size_t)r * 300 + col];
                v[0]=(__bf16)f0.x; v[1]=(__bf16)f0.y; v[2]=(__bf16)f0.z; v[3]=(__bf16)f0.w;
                v[4]=(__bf16)0.f; v[5]=(__bf16)0.f; v[6]=(__bf16)0.f; v[7]=(__bf16)0.f;
            } else {
                #pragma unroll
                for (int j = 0; j < 8; ++j) v[j] = (__bf16)0.f;
            }
            *(bf16x8*)&pa.hh_bf[(size_t)r * 320 + col] = v;
        }
    } else if (z == 1) {
        for (int idx = tid; idx < 8 * 64; idx += 256) {
            int r   = q * 8 + (idx >> 6);
            int col = (idx & 63) * 8;
            float4 f0 = *(const float4*)&pa.h_tail[(size_t)r * 512 + col];
            float4 f1 = *(const float4*)&pa.h_tail[(size_t)r * 512 + col + 4];
            bf16x8 v;
            v[0]=(__bf16)f0.x; v[1]=(__bf16)f0.y; v[2]=(__bf16)f0.z; v[3]=(__bf16)f0.w;
            v[4]=(__bf16)f1.x; v[5]=(__bf16)f1.y; v[6]=(__bf16)f1.z; v[7]=(__bf16)f1.w;
            *(bf16x8*)&pa.ht_bf[(size_t)r * 512 + col] = v;
        }
    } else if (z == 2) {
        if (q >= 24) return;
        // parallel fused bias: fb[w][n] = map_b . W[:,n] + b[n]
        float* red = (float*)SMEM;
        const int w  = q >> 3;
        const int c8 = q & 7;
        const int n  = c8 * 64 + (tid & 63);
        const int jq = tid >> 6;
        const float* W = pa.qkvw[w];
        float s = 0.f;
        for (int j = jq * 128; j < jq * 128 + 128; ++j)
            s += pa.map_b[j] * W[(size_t)j * 512 + n];
        red[tid] = s;
        __syncthreads();
        if (tid < 64) {
            float r4 = red[tid] + red[64 + tid] + red[128 + tid] + red[192 + tid]
                     + pa.qkvb[w][c8 * 64 + tid];
            pa.fb[w * 512 + c8 * 64 + tid] = r4;
        }
    } else if (z == 3) {
        if (q >= 36) return;
        const int f = q / 12, t = q % 12;
        fold_tile(pa.qkvw[f], pa.map_w, pa.F[f], t % 3, t / 3, SMEM);
    } else {
        if (q >= 64) return;
        typedef __bf16 trow[72];
        trow* T = (trow*)SMEM;
        const int jz = z - 4;
        const float* src = pa.tsrc[jz];
        __bf16* dst = pa.tdst[jz];
        const int tk = (q >> 3) * 64;
        const int tn = (q & 7) * 64;
        const int r0 = tid >> 4;
        const int c0 = (tid & 15) * 4;
        #pragma unroll
        for (int i = 0; i < 4; ++i) {
            float4 v = *(const float4*)&src[(size_t)(tk + r0 + i * 16) * 512 + tn + c0];
            T[r0 + i * 16][c0 + 0] = (__bf16)v.x;
            T[r0 + i * 16][c0 + 1] = (__bf16)v.y;
            T[r0 + i * 16][c0 + 2] = (__bf16)v.z;
            T[r0 + i * 16][c0 + 3] = (__bf16)v.w;
        }
        __syncthreads();
        const int n  = tid >> 2;
        const int kk = (tid & 3) * 16;
        bf16x8 o0, o1;
        #pragma unroll
        for (int j = 0; j < 8; ++j) { o0[j] = T[kk + j][n]; o1[j] = T[kk + 8 + j][n]; }
        __bf16* dp = dst + (size_t)(tn + n) * 512 + tk + kk;
        *(bf16x8*)dp       = o0;
        *(bf16x8*)(dp + 8) = o1;
    }
}

// ------------------------------ GEMM 128x128 -------------------------------
// C = A[M,Kp]bf16 @ W[N,Kp]bf16^T + bias; z = job select. Main loop
// byte-identical to round 7 (double-buffered global_load_lds + XOR swizzle).
struct GemmJobs {
    const __bf16* A[6];
    const __bf16* W[6];
    const float*  bias[6];
    void*         C[6];
    int           Kp[6];
};

template <typename TC>
__global__ __launch_bounds__(256) void gemm128(GemmJobs jobs) {
    __shared__ __align__(16) __bf16 As[2][4096];   // 2 x [128][32]
    __shared__ __align__(16) __bf16 Bs[2][4096];

    const int z = blockIdx.z;
    const __bf16* A    = jobs.A[z];
    const __bf16* W    = jobs.W[z];
    const float*  bias = jobs.bias[z];
    TC*           C    = (TC*)jobs.C[z];
    const int     Kp   = jobs.Kp[z];

    const int tid  = threadIdx.x;
    const int wave = tid >> 6;
    const int lane = tid & 63;
    const int quad = lane >> 4;
    const int l16  = lane & 15;
    const int wy   = wave >> 1;
    const int wx   = wave & 1;
    const int rowBase = blockIdx.y * 128;
    const int colBase = blockIdx.x * 128;

    const int s_row = tid >> 2;
    const int s_kc  = ((tid & 3) ^ ((s_row >> 1) & 3)) * 8;

    const __bf16* gA = A + (size_t)(rowBase + s_row) * Kp + s_kc;
    const __bf16* gB = W + (size_t)(colBase + s_row) * Kp + s_kc;
    const int waveOff = wave * 512;

    f32x4 acc[4][4] = {};
    const int nk = Kp >> 5;

    __builtin_amdgcn_global_load_lds(AS1(gA),                   AS3(&As[0][waveOff]),        16, 0, 0);
    __builtin_amdgcn_global_load_lds(AS1(gA + (size_t)64 * Kp), AS3(&As[0][2048 + waveOff]), 16, 0, 0);
    __builtin_amdgcn_global_load_lds(AS1(gB),                   AS3(&Bs[0][waveOff]),        16, 0, 0);
    __builtin_amdgcn_global_load_lds(AS1(gB + (size_t)64 * Kp), AS3(&Bs[0][2048 + waveOff]), 16, 0, 0);

    for (int i = 0; i < nk; ++i) {
        const int cur = i & 1;
        __syncthreads();   // drains tile i's loads; prev reads of buf[cur^1] done

        if (i + 1 < nk) {  // issue tile i+1 into the other buffer
            const int kt = (i + 1) * 32;
            const int nx = cur ^ 1;
            __builtin_amdgcn_global_load_lds(AS1(gA + kt),                   AS3(&As[nx][waveOff]),        16, 0, 0);
            __builtin_amdgcn_global_load_lds(AS1(gA + kt + (size_t)64 * Kp), AS3(&As[nx][2048 + waveOff]), 16, 0, 0);
            __builtin_amdgcn_global_load_lds(AS1(gB + kt),                   AS3(&Bs[nx][waveOff]),        16, 0, 0);
            __builtin_amdgcn_global_load_lds(AS1(gB + kt + (size_t)64 * Kp), AS3(&Bs[nx][2048 + waveOff]), 16, 0, 0);
        }

        bf16x8 ar[4], br[4];
        #pragma unroll
        for (int ii = 0; ii < 4; ++ii) {
            const int ra = wy * 64 + ii * 16 + l16;
            ar[ii] = *(const bf16x8*)&As[cur][ra * 32 + ((quad ^ ((ra >> 1) & 3)) << 3)];
        }
        #pragma unroll
        for (int jj = 0; jj < 4; ++jj) {
            const int rb = wx * 64 + jj * 16 + l16;
            br[jj] = *(const bf16x8*)&Bs[cur][rb * 32 + ((quad ^ ((rb >> 1) & 3)) << 3)];
        }
        #pragma unroll
        for (int ii = 0; ii < 4; ++ii)
            #pragma unroll
            for (int jj = 0; jj < 4; ++jj)
                acc[ii][jj] = __builtin_amdgcn_mfma_f32_16x16x32_bf16(ar[ii], br[jj], acc[ii][jj], 0, 0, 0);
    }

    // epilogue: C/D layout col=l16, row=quad*4+reg
    #pragma unroll
    for (int jj = 0; jj < 4; ++jj) {
        int col = colBase + wx * 64 + jj * 16 + l16;
        float bv = bias[col];
        #pragma unroll
        for (int ii = 0; ii < 4; ++ii) {
            #pragma unroll
            for (int r = 0; r < 4; ++r) {
                int row = rowBase + wy * 64 + ii * 16 + quad * 4 + r;
                C[(size_t)row * HID + col] = (TC)(acc[ii][jj][r] + bv);
            }
        }
    }
}

// ------------------------- MFMA flash attention ----------------------------
// grid = (head 8, batch 64, side 2). side 0: head-q x tail-k; side 1: swap.
__global__ __launch_bounds__(256) void attn_mfma(
    const __bf16* __restrict__ Q0, const __bf16* __restrict__ K0,
    const __bf16* __restrict__ Vr0, const __bf16* __restrict__ Vc0,
    const __bf16* __restrict__ Q1, const __bf16* __restrict__ K1,
    const __bf16* __restrict__ Vr1, const __bf16* __restrict__ Vc1,
    const int* __restrict__ ranges,
    __bf16* __restrict__ O0, __bf16* __restrict__ O1,
    int Nq, int Nk)
{
    __shared__ __align__(16) __bf16 Qs[64][72];
    __shared__ __align__(16) __bf16 Ks[64][72];
    __shared__ __align__(16) __bf16 Vt[64][72];   // [dim][key]
    __shared__ __align__(16) __bf16 Ps[64][72];   // [query][key]

    const int z = blockIdx.z;
    const __bf16* Q    = z ? Q1 : Q0;
    const __bf16* Kg   = z ? K1 : K0;
    const __bf16* Vres = z ? Vr1 : Vr0;
    const __bf16* Vctx = z ? Vc1 : Vc0;
    __bf16* Out        = z ? O1 : O0;
    const int* qstart  = z ? ranges + 128 : ranges;
    const int* qend    = z ? ranges + 192 : ranges + 64;
    const int* kstart  = z ? ranges       : ranges + 128;
    const int* kend    = z ? ranges + 64  : ranges + 192;

    const int h = blockIdx.x, b = blockIdx.y;
    const int qs = qstart[b], qe = qend[b];
    const int ts = kstart[b], te = kend[b];
    const int nq = qe - qs, nk = te - ts;
    if (nq <= 0) return;

    const int tid  = threadIdx.x;
    const int wave = tid >> 6;
    const int lane = tid & 63;
    const int quad = lane >> 4;
    const int l16  = lane & 15;
    const int srow = tid >> 2;
    const int scol = (tid & 3) * 16;

    if (nk <= 0) {
        float* meanv = (float*)Qs;
        if (tid < 64) {
            float s = 0.f;
            for (int m = 0; m < Nk; ++m)
                s += (float)Vctx[(size_t)m * HID + h * 64 + tid];
            meanv[tid] = s / (float)Nk;
        }
        __syncthreads();
        int d = tid & 63;
        for (int r = qs + (tid >> 6); r < qe; r += 4) {
            size_t off = (size_t)r * HID + h * 64 + d;
            Out[off] = (__bf16)((float)Vres[off] + meanv[d]);
        }
        return;
    }

    for (int qc = 0; qc < nq; qc += 64) {
        __syncthreads();
        {
            int qg = min(qs + qc + srow, Nq - 1);
            const __bf16* src = Q + (size_t)qg * HID + h * 64 + scol;
            *(bf16x8*)&Qs[srow][scol]     = *(const bf16x8*)src;
            *(bf16x8*)&Qs[srow][scol + 8] = *(const bf16x8*)(src + 8);
        }
        __syncthreads();
        bf16x8 aq0 = *(const bf16x8*)&Qs[wave * 16 + l16][quad * 8];
        bf16x8 aq1 = *(const bf16x8*)&Qs[wave * 16 + l16][32 + quad * 8];

        f32x4 O[4] = {};
        float Mx[4], L[4];
        #pragma unroll
        for (int r = 0; r < 4; ++r) { Mx[r] = -__builtin_inff(); L[r] = 0.f; }

        for (int kc = 0; kc < nk; kc += 64) {
            __syncthreads();
            {
                int kg = min(ts + kc + srow, Nk - 1);
                const __bf16* ksrc = Kg + (size_t)kg * HID + h * 64 + scol;
                *(bf16x8*)&Ks[srow][scol]     = *(const bf16x8*)ksrc;
                *(bf16x8*)&Ks[srow][scol + 8] = *(const bf16x8*)(ksrc + 8);
                const __bf16* vsrc = Vctx + (size_t)kg * HID + h * 64 + scol;
                bf16x8 v0 = *(const bf16x8*)vsrc;
                bf16x8 v1 = *(const bf16x8*)(vsrc + 8);
                #pragma unroll
                for (int j = 0; j < 8; ++j) {
                    Vt[scol + j][srow]     = v0[j];
                    Vt[scol + 8 + j][srow] = v1[j];
                }
            }
            __syncthreads();

            f32x4 S[4] = {};
            #pragma unroll
            for (int c = 0; c < 4; ++c) {
                bf16x8 bk0 = *(const bf16x8*)&Ks[c * 16 + l16][quad * 8];
                bf16x8 bk1 = *(const bf16x8*)&Ks[c * 16 + l16][32 + quad * 8];
                S[c] = __builtin_amdgcn_mfma_f32_16x16x32_bf16(aq0, bk0, S[c], 0, 0, 0);
                S[c] = __builtin_amdgcn_mfma_f32_16x16x32_bf16(aq1, bk1, S[c], 0, 0, 0);
            }

            #pragma unroll
            for (int c = 0; c < 4; ++c) {
                bool valid = (ts + kc + c * 16 + l16) < te;
                #pragma unroll
                for (int r = 0; r < 4; ++r)
                    S[c][r] = valid ? S[c][r] * 0.125f : -__builtin_inff();
            }

            float cm[4], ps[4], alpha[4];
            #pragma unroll
            for (int r = 0; r < 4; ++r) {
                float v = fmaxf(fmaxf(S[0][r], S[1][r]), fmaxf(S[2][r], S[3][r]));
                v = fmaxf(v, __shfl_xor(v, 1, 64));
                v = fmaxf(v, __shfl_xor(v, 2, 64));
                v = fmaxf(v, __shfl_xor(v, 4, 64));
                v = fmaxf(v, __shfl_xor(v, 8, 64));
                cm[r] = v;
            }
            #pragma unroll
            for (int r = 0; r < 4; ++r) {
                float nM = fmaxf(Mx[r], cm[r]);
                alpha[r] = __expf(Mx[r] - nM);
                Mx[r] = nM;
                ps[r] = 0.f;
            }
            #pragma unroll
            for (int c = 0; c < 4; ++c)
                #pragma unroll
                for (int r = 0; r < 4; ++r) {
                    float p = __expf(S[c][r] - Mx[r]);
                    S[c][r] = p;
                    ps[r] += p;
                }
            #pragma unroll
            for (int r = 0; r < 4; ++r) {
                float v = ps[r];
                v += __shfl_xor(v, 1, 64);
                v += __shfl_xor(v, 2, 64);
                v += __shfl_xor(v, 4, 64);
                v += __shfl_xor(v, 8, 64);
                L[r] = L[r] * alpha[r] + v;
            }
            #pragma unroll
            for (int c = 0; c < 4; ++c)
                #pragma unroll
                for (int r = 0; r < 4; ++r)
                    O[c][r] *= alpha[r];

            #pragma unroll
            for (int c = 0; c < 4; ++c)
                #pragma unroll
                for (int r = 0; r < 4; ++r)
                    Ps[wave * 16 + quad * 4 + r][c * 16 + l16] = (__bf16)S[c][r];
            __syncthreads();

            bf16x8 ap0 = *(const bf16x8*)&Ps[wave * 16 + l16][quad * 8];
            bf16x8 ap1 = *(const bf16x8*)&Ps[wave * 16 + l16][32 + quad * 8];
            #pragma unroll
            for (int c = 0; c < 4; ++c) {
                bf16x8 bv0 = *(const bf16x8*)&Vt[c * 16 + l16][quad * 8];
                bf16x8 bv1 = *(const bf16x8*)&Vt[c * 16 + l16][32 + quad * 8];
                O[c] = __builtin_amdgcn_mfma_f32_16x16x32_bf16(ap0, bv0, O[c], 0, 0, 0);
                O[c] = __builtin_amdgcn_mfma_f32_16x16x32_bf16(ap1, bv1, O[c], 0, 0, 0);
            }
        }

        #pragma unroll
        for (int c = 0; c < 4; ++c) {
            int d = h * 64 + c * 16 + l16;
            #pragma unroll
            for (int r = 0; r < 4; ++r) {
                int qrow = qs + qc + wave * 16 + quad * 4 + r;
                if (qrow < qe) {
                    size_t off = (size_t)qrow * HID + d;
                    Out[off] = (__bf16)((float)Vres[off] + O[c][r] / L[r]);
                }
            }
        }
    }
}

// ------------------------------ launcher -----------------------------------
extern "C" void kernel_launch(void* const* d_in, const int* in_sizes, int n_in,
                              void* d_out, int out_size, void* d_ws, size_t ws_size,
                              hipStream_t stream) {
    (void)in_sizes; (void)n_in; (void)out_size; (void)ws_size;

    const float* h_head = (const float*)d_in[0];
    const float* h_tail = (const float*)d_in[1];
    const int* batch_head = (const int*)d_in[2];
    const int* batch_tail = (const int*)d_in[3];
    const float* map_w = (const float*)d_in[4];
    const float* map_b = (const float*)d_in[5];
    const float* q1_w = (const float*)d_in[6];
    const float* q1_b = (const float*)d_in[7];
    const float* k1_w = (const float*)d_in[8];
    const float* k1_b = (const float*)d_in[9];
    const float* v1_w = (const float*)d_in[10];
    const float* v1_b = (const float*)d_in[11];
    const float* q2_w = (const float*)d_in[12];
    const float* q2_b = (const float*)d_in[13];
    const float* k2_w = (const float*)d_in[14];
    const float* k2_b = (const float*)d_in[15];
    const float* v2_w = (const float*)d_in[16];
    const float* v2_b = (const float*)d_in[17];
    const float* d1_w = (const float*)d_in[18];
    const float* d1_b = (const float*)d_in[19];
    const float* d2_w = (const float*)d_in[20];
    const float* d2_b = (const float*)d_in[21];

    float* out = (float*)d_out;

    const size_t SZ = (size_t)NTOK * HID;
    char* ws = (char*)d_ws;
    int* ranges   = (int*)ws;                            // 1 KB
    __bf16* hh_bf = (__bf16*)(ws + 1024);                // [4096][320]
    __bf16* ht_bf = hh_bf + (size_t)NTOK * 320;          // [4096][512]
    __bf16* q2T  = ht_bf + SZ;                           // [512][512] each
    __bf16* k2T  = q2T + 512 * 512;
    __bf16* v2T  = k2T + 512 * 512;
    __bf16* d1T  = v2T + 512 * 512;
    __bf16* d2T  = d1T + 512 * 512;
    __bf16* FqT  = d2T + 512 * 512;                      // [512][320] each
    __bf16* FkT  = FqT + 512 * 320;
    __bf16* FvT  = FkT + 512 * 320;
    __bf16* qh   = FvT + 512 * 320;                      // [4096][512] each
    __bf16* kh   = qh  + SZ;
    __bf16* vh   = kh  + SZ;
    __bf16* qt   = vh  + SZ;
    __bf16* kt   = qt  + SZ;
    __bf16* vt   = kt  + SZ;
    __bf16* ctxh = vt  + SZ;
    __bf16* ctxt = ctxh + SZ;
    float*  fb   = (float*)(ctxt + SZ);                  // [3][512] fp32

    // D1: all leaf work (casts, ranges, fb, transposes, fold)
    PrepArgs pa;
    pa.h_head = h_head; pa.h_tail = h_tail;
    pa.bh = batch_head; pa.bt = batch_tail;
    pa.map_w = map_w; pa.map_b = map_b;
    pa.qkvw[0] = q1_w; pa.qkvw[1] = k1_w; pa.qkvw[2] = v1_w;
    pa.qkvb[0] = q1_b; pa.qkvb[1] = k1_b; pa.qkvb[2] = v1_b;
    const float* wsrc[5] = {q2_w, k2_w, v2_w, d1_w, d2_w};
    __bf16* wdst[5] = {q2T, k2T, v2T, d1T, d2T};
    for (int i = 0; i < 5; ++i) { pa.tsrc[i] = wsrc[i]; pa.tdst[i] = wdst[i]; }
    pa.hh_bf = hh_bf; pa.ht_bf = ht_bf;
    pa.F[0] = FqT; pa.F[1] = FkT; pa.F[2] = FvT;
    pa.fb = fb; pa.ranges = ranges;
    fused_prep<<<dim3(512, 1, 9), dim3(256), 0, stream>>>(pa);

    // D2: ALL 6 qkv GEMMs (head Kp=320 via folded weights, tail Kp=512)
    {
        GemmJobs j;
        j.A[0] = hh_bf; j.W[0] = FqT; j.bias[0] = fb;        j.C[0] = qh; j.Kp[0] = 320;
        j.A[1] = hh_bf; j.W[1] = FkT; j.bias[1] = fb + 512;  j.C[1] = kh; j.Kp[1] = 320;
        j.A[2] = hh_bf; j.W[2] = FvT; j.bias[2] = fb + 1024; j.C[2] = vh; j.Kp[2] = 320;
        j.A[3] = ht_bf; j.W[3] = q2T; j.bias[3] = q2_b;      j.C[3] = qt; j.Kp[3] = 512;
        j.A[4] = ht_bf; j.W[4] = k2T; j.bias[4] = k2_b;      j.C[4] = kt; j.Kp[4] = 512;
        j.A[5] = ht_bf; j.W[5] = v2T; j.bias[5] = v2_b;      j.C[5] = vt; j.Kp[5] = 512;
        gemm128<__bf16><<<dim3(4, 32, 6), dim3(256), 0, stream>>>(j);
    }

    // D3: attention (both sides, one dispatch)
    attn_mfma<<<dim3(8, 64, 2), dim3(256), 0, stream>>>(
        qh, kt, vh, vt,
        qt, kh, vt, vh,
        ranges, ctxh, ctxt, NTOK, NTOK);

    // D4: output projections (fp32 into d_out)
    {
        GemmJobs j;
        j.A[0] = ctxh; j.W[0] = d1T; j.bias[0] = d1_b; j.C[0] = out;      j.Kp[0] = 512;
        j.A[1] = ctxt; j.W[1] = d2T; j.bias[1] = d2_b; j.C[1] = out + SZ; j.Kp[1] = 512;
        j.A[2] = ctxt; j.W[2] = d2T; j.bias[2] = d2_b; j.C[2] = out + SZ; j.Kp[2] = 512;
        j.A[3] = ctxt; j.W[3] = d2T; j.bias[3] = d2_b; j.C[3] = out + SZ; j.Kp[3] = 512;
        j.A[4] = ctxt; j.W[4] = d2T; j.bias[4] = d2_b; j.C[4] = out + SZ; j.Kp[4] = 512;
        j.A[5] = ctxt; j.W[5] = d2T; j.bias[5] = d2_b; j.C[5] = out + SZ; j.Kp[5] = 512;
        gemm128<float><<<dim3(4, 32, 2), dim3(256), 0, stream>>>(j);
    }
}

// Round 6
// 184.022 us; speedup vs baseline: 2.1389x; 1.0777x over previous
//
#include <hip/hip_runtime.h>
#include <hip/hip_bf16.h>
#include <math.h>

// ---------------------------------------------------------------------------
// CrossModalityMultiHeadAttention  (MI355X / gfx950)
// Round 13 == Round 12 resubmitted verbatim (bench infra failed twice; no
// measurement was obtained; kernel re-audited for hang risk: none found).
// Depth-4 graph; fold made latency-correct.
// R11 counters: fused_prep 45.8us @ 5% occupancy / 610 GB/s -- the 36 fold
// blocks (16 SERIAL iters, no prefetch, 16 scattered ds_write_b16/thread)
// + 24 fb blocks ran ~35us nearly alone. Fixes:
//   - fb DELETED: map_b rides as row k=300 of the fold B-operand and the
//     head cast writes hh_bf[:,300]=1.0 -> head bias is plain q1_b.
//   - fold_tile: register prefetch (iter i+1 fp32 loads issued during iter
//     i's MFMA window) + 4x4 in-register transpose -> 4x ds_write_b64
//     instead of 16x scattered ds_write_b16.
// Graph: D1 prep(casts+ranges+5 transposes+fold) -> D2 all-6 qkv ->
//        D3 attn -> D4 out-proj.  GEMM/attn bodies byte-identical to R7.
// ---------------------------------------------------------------------------

typedef __bf16 bf16x8 __attribute__((ext_vector_type(8)));
typedef __bf16 bf16x4 __attribute__((ext_vector_type(4)));
typedef float  f32x4  __attribute__((ext_vector_type(4)));

#define HID 512
#define NTOK 4096

#define AS1(p) ((const __attribute__((address_space(1))) void*)(p))
#define AS3(p) ((__attribute__((address_space(3))) void*)(p))

// ------------------------------ fold tile ----------------------------------
// F[n][k] = sum_j Wf[j][n] * Mrow(k)[j],  Mrow(k) = map_w[k] (k<300),
// map_b (k==300), 0 (k>300).  Register-prefetched fp32 staging.
__device__ __forceinline__ void fold_tile(
    const float* __restrict__ Wf,   // [512][512] fp32
    const float* __restrict__ Mw,   // [300][512] fp32
    const float* __restrict__ Mb,   // [512] fp32
    __bf16* __restrict__ F,         // [512][320] bf16 out
    int bx, int by, char* SMEM)
{
    __bf16* As = (__bf16*)SMEM;            // [128][32]
    __bf16* Bs = (__bf16*)(SMEM + 8192);   // [128][32]

    const int tid  = threadIdx.x;
    const int wave = tid >> 6;
    const int lane = tid & 63;
    const int quad = lane >> 4;
    const int l16  = lane & 15;
    const int wy   = wave >> 1;
    const int wx   = wave & 1;
    const int rowBase = by * 128;   // n
    const int colBase = bx * 128;   // k

    // B staging map (matches gemm128's global_load_lds slot layout)
    const int s_row = tid >> 2;
    const int s_gc  = (tid & 3) ^ ((s_row >> 1) & 3);   // global j-chunk
    // A staging map: 4x4 register transpose
    const int a_j4 = (tid & 7) * 4;     // j-offset within 32-step
    const int a_n4 = (tid >> 3) * 4;    // n-offset within 128

    float aR[16];
    float4 b0lo, b0hi, b1lo, b1hi;

    auto loadA = [&](int j0) {
        #pragma unroll
        for (int u = 0; u < 4; ++u)
            *(float4*)&aR[u * 4] =
                *(const float4*)&Wf[(size_t)(j0 + a_j4 + u) * 512 + rowBase + a_n4];
    };
    auto loadRow = [&](int k, int jc, float4& lo, float4& hi) {
        if (k < 300) {
            lo = *(const float4*)&Mw[(size_t)k * 512 + jc];
            hi = *(const float4*)&Mw[(size_t)k * 512 + jc + 4];
        } else if (k == 300) {
            lo = *(const float4*)&Mb[jc];
            hi = *(const float4*)&Mb[jc + 4];
        } else {
            lo = float4{0.f, 0.f, 0.f, 0.f};
            hi = float4{0.f, 0.f, 0.f, 0.f};
        }
    };
    auto loadB = [&](int j0) {
        const int jc = j0 + s_gc * 8;
        loadRow(colBase + s_row,      jc, b0lo, b0hi);
        loadRow(colBase + 64 + s_row, jc, b1lo, b1hi);
    };

    f32x4 acc[4][4] = {};

    loadA(0);
    loadB(0);

    for (int i = 0; i < 16; ++i) {
        __syncthreads();   // previous MFMA done reading LDS
        // regs -> LDS
        #pragma unroll
        for (int v = 0; v < 4; ++v) {
            const int r = a_n4 + v;
            const int p = (a_j4 >> 3) ^ ((r >> 1) & 3);
            bf16x4 w;
            w[0] = (__bf16)aR[0 * 4 + v];
            w[1] = (__bf16)aR[1 * 4 + v];
            w[2] = (__bf16)aR[2 * 4 + v];
            w[3] = (__bf16)aR[3 * 4 + v];
            *(bf16x4*)&As[r * 32 + p * 8 + (a_j4 & 7)] = w;
        }
        {
            bf16x8 v0, v1;
            v0[0]=(__bf16)b0lo.x; v0[1]=(__bf16)b0lo.y; v0[2]=(__bf16)b0lo.z; v0[3]=(__bf16)b0lo.w;
            v0[4]=(__bf16)b0hi.x; v0[5]=(__bf16)b0hi.y; v0[6]=(__bf16)b0hi.z; v0[7]=(__bf16)b0hi.w;
            v1[0]=(__bf16)b1lo.x; v1[1]=(__bf16)b1lo.y; v1[2]=(__bf16)b1lo.z; v1[3]=(__bf16)b1lo.w;
            v1[4]=(__bf16)b1hi.x; v1[5]=(__bf16)b1hi.y; v1[6]=(__bf16)b1hi.z; v1[7]=(__bf16)b1hi.w;
            *(bf16x8*)&Bs[tid * 8]        = v0;
            *(bf16x8*)&Bs[2048 + tid * 8] = v1;
        }
        // prefetch next iter while MFMA runs
        if (i + 1 < 16) { loadA((i + 1) * 32); loadB((i + 1) * 32); }
        __syncthreads();   // LDS writes visible

        bf16x8 ar[4], br[4];
        #pragma unroll
        for (int ii = 0; ii < 4; ++ii) {
            const int ra = wy * 64 + ii * 16 + l16;
            ar[ii] = *(const bf16x8*)&As[ra * 32 + ((quad ^ ((ra >> 1) & 3)) << 3)];
        }
        #pragma unroll
        for (int jj = 0; jj < 4; ++jj) {
            const int rb = wx * 64 + jj * 16 + l16;
            br[jj] = *(const bf16x8*)&Bs[rb * 32 + ((quad ^ ((rb >> 1) & 3)) << 3)];
        }
        #pragma unroll
        for (int ii = 0; ii < 4; ++ii)
            #pragma unroll
            for (int jj = 0; jj < 4; ++jj)
                acc[ii][jj] = __builtin_amdgcn_mfma_f32_16x16x32_bf16(ar[ii], br[jj], acc[ii][jj], 0, 0, 0);
    }

    // epilogue: F[n][k], ldC=320, mask k<320
    #pragma unroll
    for (int jj = 0; jj < 4; ++jj) {
        int col = colBase + wx * 64 + jj * 16 + l16;
        if (col < 320) {
            #pragma unroll
            for (int ii = 0; ii < 4; ++ii) {
                #pragma unroll
                for (int r = 0; r < 4; ++r) {
                    int row = rowBase + wy * 64 + ii * 16 + quad * 4 + r;
                    F[(size_t)row * 320 + col] = (__bf16)acc[ii][jj][r];
                }
            }
        }
    }
}

// --------------------- fused prep (depth-4 leaf work) ----------------------
// grid (512, 1, 8):
//   z=0 : h_head fp32 -> hh_bf [4096][320] (col300=1.0, 301..319=0) + ranges
//   z=1 : h_tail fp32 -> ht_bf [4096][512]
//   z=2 : q<36 : fold tiles (f = q/12, tile = q%12)
//   z=3..7 : weight transpose (q2,k2,v2,d1,d2), q<64 each
struct PrepArgs {
    const float* h_head; const float* h_tail;
    const int* bh; const int* bt;
    const float* map_w; const float* map_b;
    const float* qkvw[3];                         // q1,k1,v1 fp32
    const float* tsrc[5]; __bf16* tdst[5];        // q2,k2,v2,d1,d2
    __bf16* hh_bf; __bf16* ht_bf;
    __bf16* F[3];
    int* ranges;
};

__global__ __launch_bounds__(256) void fused_prep(PrepArgs pa) {
    const int q = blockIdx.x, z = blockIdx.z, tid = threadIdx.x;
    __shared__ __align__(16) char SMEM[16384];

    if (z == 0) {
        if (q == 0 && tid < 128) {
            int b = tid & 63;
            const int* arr = (tid < 64) ? pa.bh : pa.bt;
            int base = (tid < 64) ? 0 : 128;
            int lo = 0, hi = NTOK;
            while (lo < hi) { int mid = (lo + hi) >> 1; if (arr[mid] < b) lo = mid + 1; else hi = mid; }
            int start = lo;
            lo = 0; hi = NTOK;
            while (lo < hi) { int mid = (lo + hi) >> 1; if (arr[mid] <= b) lo = mid + 1; else hi = mid; }
            pa.ranges[base + b] = start;
            pa.ranges[base + 64 + b] = lo;
        }
        for (int idx = tid; idx < 8 * 40; idx += 256) {
            int r   = q * 8 + idx / 40;
            int col = (idx % 40) * 8;
            bf16x8 v;
            if (col + 8 <= 300) {
                float4 f0 = *(const float4*)&pa.h_head[(size_t)r * 300 + col];
                float4 f1 = *(const float4*)&pa.h_head[(size_t)r * 300 + col + 4];
                v[0]=(__bf16)f0.x; v[1]=(__bf16)f0.y; v[2]=(__bf16)f0.z; v[3]=(__bf16)f0.w;
                v[4]=(__bf16)f1.x; v[5]=(__bf16)f1.y; v[6]=(__bf16)f1.z; v[7]=(__bf16)f1.w;
            } else if (col < 300) {  // col == 296: 4 valid + one(k=300) + pad
                float4 f0 = *(const float4*)&pa.h_head[(size_t)r * 300 + col];
                v[0]=(__bf16)f0.x; v[1]=(__bf16)f0.y; v[2]=(__bf16)f0.z; v[3]=(__bf16)f0.w;
                v[4]=(__bf16)1.0f;  // col 300: constant-1 column (bias fold)
                v[5]=(__bf16)0.f; v[6]=(__bf16)0.f; v[7]=(__bf16)0.f;
            } else {
                #pragma unroll
                for (int j = 0; j < 8; ++j) v[j] = (__bf16)0.f;
            }
            *(bf16x8*)&pa.hh_bf[(size_t)r * 320 + col] = v;
        }
    } else if (z == 1) {
        for (int idx = tid; idx < 8 * 64; idx += 256) {
            int r   = q * 8 + (idx >> 6);
            int col = (idx & 63) * 8;
            float4 f0 = *(const float4*)&pa.h_tail[(size_t)r * 512 + col];
            float4 f1 = *(const float4*)&pa.h_tail[(size_t)r * 512 + col + 4];
            bf16x8 v;
            v[0]=(__bf16)f0.x; v[1]=(__bf16)f0.y; v[2]=(__bf16)f0.z; v[3]=(__bf16)f0.w;
            v[4]=(__bf16)f1.x; v[5]=(__bf16)f1.y; v[6]=(__bf16)f1.z; v[7]=(__bf16)f1.w;
            *(bf16x8*)&pa.ht_bf[(size_t)r * 512 + col] = v;
        }
    } else if (z == 2) {
        if (q >= 36) return;
        const int f = q / 12, t = q % 12;
        fold_tile(pa.qkvw[f], pa.map_w, pa.map_b, pa.F[f], t % 3, t / 3, SMEM);
    } else {
        if (q >= 64) return;
        typedef __bf16 trow[72];
        trow* T = (trow*)SMEM;
        const int jz = z - 3;
        const float* src = pa.tsrc[jz];
        __bf16* dst = pa.tdst[jz];
        const int tk = (q >> 3) * 64;
        const int tn = (q & 7) * 64;
        const int r0 = tid >> 4;
        const int c0 = (tid & 15) * 4;
        #pragma unroll
        for (int i = 0; i < 4; ++i) {
            float4 v = *(const float4*)&src[(size_t)(tk + r0 + i * 16) * 512 + tn + c0];
            T[r0 + i * 16][c0 + 0] = (__bf16)v.x;
            T[r0 + i * 16][c0 + 1] = (__bf16)v.y;
            T[r0 + i * 16][c0 + 2] = (__bf16)v.z;
            T[r0 + i * 16][c0 + 3] = (__bf16)v.w;
        }
        __syncthreads();
        const int n  = tid >> 2;
        const int kk = (tid & 3) * 16;
        bf16x8 o0, o1;
        #pragma unroll
        for (int j = 0; j < 8; ++j) { o0[j] = T[kk + j][n]; o1[j] = T[kk + 8 + j][n]; }
        __bf16* dp = dst + (size_t)(tn + n) * 512 + tk + kk;
        *(bf16x8*)dp       = o0;
        *(bf16x8*)(dp + 8) = o1;
    }
}

// ------------------------------ GEMM 128x128 -------------------------------
// C = A[M,Kp]bf16 @ W[N,Kp]bf16^T + bias; z = job select. Main loop
// byte-identical to round 7 (double-buffered global_load_lds + XOR swizzle).
struct GemmJobs {
    const __bf16* A[6];
    const __bf16* W[6];
    const float*  bias[6];
    void*         C[6];
    int           Kp[6];
};

template <typename TC>
__global__ __launch_bounds__(256) void gemm128(GemmJobs jobs) {
    __shared__ __align__(16) __bf16 As[2][4096];   // 2 x [128][32]
    __shared__ __align__(16) __bf16 Bs[2][4096];

    const int z = blockIdx.z;
    const __bf16* A    = jobs.A[z];
    const __bf16* W    = jobs.W[z];
    const float*  bias = jobs.bias[z];
    TC*           C    = (TC*)jobs.C[z];
    const int     Kp   = jobs.Kp[z];

    const int tid  = threadIdx.x;
    const int wave = tid >> 6;
    const int lane = tid & 63;
    const int quad = lane >> 4;
    const int l16  = lane & 15;
    const int wy   = wave >> 1;
    const int wx   = wave & 1;
    const int rowBase = blockIdx.y * 128;
    const int colBase = blockIdx.x * 128;

    const int s_row = tid >> 2;
    const int s_kc  = ((tid & 3) ^ ((s_row >> 1) & 3)) * 8;

    const __bf16* gA = A + (size_t)(rowBase + s_row) * Kp + s_kc;
    const __bf16* gB = W + (size_t)(colBase + s_row) * Kp + s_kc;
    const int waveOff = wave * 512;

    f32x4 acc[4][4] = {};
    const int nk = Kp >> 5;

    __builtin_amdgcn_global_load_lds(AS1(gA),                   AS3(&As[0][waveOff]),        16, 0, 0);
    __builtin_amdgcn_global_load_lds(AS1(gA + (size_t)64 * Kp), AS3(&As[0][2048 + waveOff]), 16, 0, 0);
    __builtin_amdgcn_global_load_lds(AS1(gB),                   AS3(&Bs[0][waveOff]),        16, 0, 0);
    __builtin_amdgcn_global_load_lds(AS1(gB + (size_t)64 * Kp), AS3(&Bs[0][2048 + waveOff]), 16, 0, 0);

    for (int i = 0; i < nk; ++i) {
        const int cur = i & 1;
        __syncthreads();   // drains tile i's loads; prev reads of buf[cur^1] done

        if (i + 1 < nk) {  // issue tile i+1 into the other buffer
            const int kt = (i + 1) * 32;
            const int nx = cur ^ 1;
            __builtin_amdgcn_global_load_lds(AS1(gA + kt),                   AS3(&As[nx][waveOff]),        16, 0, 0);
            __builtin_amdgcn_global_load_lds(AS1(gA + kt + (size_t)64 * Kp), AS3(&As[nx][2048 + waveOff]), 16, 0, 0);
            __builtin_amdgcn_global_load_lds(AS1(gB + kt),                   AS3(&Bs[nx][waveOff]),        16, 0, 0);
            __builtin_amdgcn_global_load_lds(AS1(gB + kt + (size_t)64 * Kp), AS3(&Bs[nx][2048 + waveOff]), 16, 0, 0);
        }

        bf16x8 ar[4], br[4];
        #pragma unroll
        for (int ii = 0; ii < 4; ++ii) {
            const int ra = wy * 64 + ii * 16 + l16;
            ar[ii] = *(const bf16x8*)&As[cur][ra * 32 + ((quad ^ ((ra >> 1) & 3)) << 3)];
        }
        #pragma unroll
        for (int jj = 0; jj < 4; ++jj) {
            const int rb = wx * 64 + jj * 16 + l16;
            br[jj] = *(const bf16x8*)&Bs[cur][rb * 32 + ((quad ^ ((rb >> 1) & 3)) << 3)];
        }
        #pragma unroll
        for (int ii = 0; ii < 4; ++ii)
            #pragma unroll
            for (int jj = 0; jj < 4; ++jj)
                acc[ii][jj] = __builtin_amdgcn_mfma_f32_16x16x32_bf16(ar[ii], br[jj], acc[ii][jj], 0, 0, 0);
    }

    // epilogue: C/D layout col=l16, row=quad*4+reg
    #pragma unroll
    for (int jj = 0; jj < 4; ++jj) {
        int col = colBase + wx * 64 + jj * 16 + l16;
        float bv = bias[col];
        #pragma unroll
        for (int ii = 0; ii < 4; ++ii) {
            #pragma unroll
            for (int r = 0; r < 4; ++r) {
                int row = rowBase + wy * 64 + ii * 16 + quad * 4 + r;
                C[(size_t)row * HID + col] = (TC)(acc[ii][jj][r] + bv);
            }
        }
    }
}

// ------------------------- MFMA flash attention ----------------------------
// grid = (head 8, batch 64, side 2). side 0: head-q x tail-k; side 1: swap.
__global__ __launch_bounds__(256) void attn_mfma(
    const __bf16* __restrict__ Q0, const __bf16* __restrict__ K0,
    const __bf16* __restrict__ Vr0, const __bf16* __restrict__ Vc0,
    const __bf16* __restrict__ Q1, const __bf16* __restrict__ K1,
    const __bf16* __restrict__ Vr1, const __bf16* __restrict__ Vc1,
    const int* __restrict__ ranges,
    __bf16* __restrict__ O0, __bf16* __restrict__ O1,
    int Nq, int Nk)
{
    __shared__ __align__(16) __bf16 Qs[64][72];
    __shared__ __align__(16) __bf16 Ks[64][72];
    __shared__ __align__(16) __bf16 Vt[64][72];   // [dim][key]
    __shared__ __align__(16) __bf16 Ps[64][72];   // [query][key]

    const int z = blockIdx.z;
    const __bf16* Q    = z ? Q1 : Q0;
    const __bf16* Kg   = z ? K1 : K0;
    const __bf16* Vres = z ? Vr1 : Vr0;
    const __bf16* Vctx = z ? Vc1 : Vc0;
    __bf16* Out        = z ? O1 : O0;
    const int* qstart  = z ? ranges + 128 : ranges;
    const int* qend    = z ? ranges + 192 : ranges + 64;
    const int* kstart  = z ? ranges       : ranges + 128;
    const int* kend    = z ? ranges + 64  : ranges + 192;

    const int h = blockIdx.x, b = blockIdx.y;
    const int qs = qstart[b], qe = qend[b];
    const int ts = kstart[b], te = kend[b];
    const int nq = qe - qs, nk = te - ts;
    if (nq <= 0) return;

    const int tid  = threadIdx.x;
    const int wave = tid >> 6;
    const int lane = tid & 63;
    const int quad = lane >> 4;
    const int l16  = lane & 15;
    const int srow = tid >> 2;
    const int scol = (tid & 3) * 16;

    if (nk <= 0) {
        float* meanv = (float*)Qs;
        if (tid < 64) {
            float s = 0.f;
            for (int m = 0; m < Nk; ++m)
                s += (float)Vctx[(size_t)m * HID + h * 64 + tid];
            meanv[tid] = s / (float)Nk;
        }
        __syncthreads();
        int d = tid & 63;
        for (int r = qs + (tid >> 6); r < qe; r += 4) {
            size_t off = (size_t)r * HID + h * 64 + d;
            Out[off] = (__bf16)((float)Vres[off] + meanv[d]);
        }
        return;
    }

    for (int qc = 0; qc < nq; qc += 64) {
        __syncthreads();
        {
            int qg = min(qs + qc + srow, Nq - 1);
            const __bf16* src = Q + (size_t)qg * HID + h * 64 + scol;
            *(bf16x8*)&Qs[srow][scol]     = *(const bf16x8*)src;
            *(bf16x8*)&Qs[srow][scol + 8] = *(const bf16x8*)(src + 8);
        }
        __syncthreads();
        bf16x8 aq0 = *(const bf16x8*)&Qs[wave * 16 + l16][quad * 8];
        bf16x8 aq1 = *(const bf16x8*)&Qs[wave * 16 + l16][32 + quad * 8];

        f32x4 O[4] = {};
        float Mx[4], L[4];
        #pragma unroll
        for (int r = 0; r < 4; ++r) { Mx[r] = -__builtin_inff(); L[r] = 0.f; }

        for (int kc = 0; kc < nk; kc += 64) {
            __syncthreads();
            {
                int kg = min(ts + kc + srow, Nk - 1);
                const __bf16* ksrc = Kg + (size_t)kg * HID + h * 64 + scol;
                *(bf16x8*)&Ks[srow][scol]     = *(const bf16x8*)ksrc;
                *(bf16x8*)&Ks[srow][scol + 8] = *(const bf16x8*)(ksrc + 8);
                const __bf16* vsrc = Vctx + (size_t)kg * HID + h * 64 + scol;
                bf16x8 v0 = *(const bf16x8*)vsrc;
                bf16x8 v1 = *(const bf16x8*)(vsrc + 8);
                #pragma unroll
                for (int j = 0; j < 8; ++j) {
                    Vt[scol + j][srow]     = v0[j];
                    Vt[scol + 8 + j][srow] = v1[j];
                }
            }
            __syncthreads();

            f32x4 S[4] = {};
            #pragma unroll
            for (int c = 0; c < 4; ++c) {
                bf16x8 bk0 = *(const bf16x8*)&Ks[c * 16 + l16][quad * 8];
                bf16x8 bk1 = *(const bf16x8*)&Ks[c * 16 + l16][32 + quad * 8];
                S[c] = __builtin_amdgcn_mfma_f32_16x16x32_bf16(aq0, bk0, S[c], 0, 0, 0);
                S[c] = __builtin_amdgcn_mfma_f32_16x16x32_bf16(aq1, bk1, S[c], 0, 0, 0);
            }

            #pragma unroll
            for (int c = 0; c < 4; ++c) {
                bool valid = (ts + kc + c * 16 + l16) < te;
                #pragma unroll
                for (int r = 0; r < 4; ++r)
                    S[c][r] = valid ? S[c][r] * 0.125f : -__builtin_inff();
            }

            float cm[4], ps[4], alpha[4];
            #pragma unroll
            for (int r = 0; r < 4; ++r) {
                float v = fmaxf(fmaxf(S[0][r], S[1][r]), fmaxf(S[2][r], S[3][r]));
                v = fmaxf(v, __shfl_xor(v, 1, 64));
                v = fmaxf(v, __shfl_xor(v, 2, 64));
                v = fmaxf(v, __shfl_xor(v, 4, 64));
                v = fmaxf(v, __shfl_xor(v, 8, 64));
                cm[r] = v;
            }
            #pragma unroll
            for (int r = 0; r < 4; ++r) {
                float nM = fmaxf(Mx[r], cm[r]);
                alpha[r] = __expf(Mx[r] - nM);
                Mx[r] = nM;
                ps[r] = 0.f;
            }
            #pragma unroll
            for (int c = 0; c < 4; ++c)
                #pragma unroll
                for (int r = 0; r < 4; ++r) {
                    float p = __expf(S[c][r] - Mx[r]);
                    S[c][r] = p;
                    ps[r] += p;
                }
            #pragma unroll
            for (int r = 0; r < 4; ++r) {
                float v = ps[r];
                v += __shfl_xor(v, 1, 64);
                v += __shfl_xor(v, 2, 64);
                v += __shfl_xor(v, 4, 64);
                v += __shfl_xor(v, 8, 64);
                L[r] = L[r] * alpha[r] + v;
            }
            #pragma unroll
            for (int c = 0; c < 4; ++c)
                #pragma unroll
                for (int r = 0; r < 4; ++r)
                    O[c][r] *= alpha[r];

            #pragma unroll
            for (int c = 0; c < 4; ++c)
                #pragma unroll
                for (int r = 0; r < 4; ++r)
                    Ps[wave * 16 + quad * 4 + r][c * 16 + l16] = (__bf16)S[c][r];
            __syncthreads();

            bf16x8 ap0 = *(const bf16x8*)&Ps[wave * 16 + l16][quad * 8];
            bf16x8 ap1 = *(const bf16x8*)&Ps[wave * 16 + l16][32 + quad * 8];
            #pragma unroll
            for (int c = 0; c < 4; ++c) {
                bf16x8 bv0 = *(const bf16x8*)&Vt[c * 16 + l16][quad * 8];
                bf16x8 bv1 = *(const bf16x8*)&Vt[c * 16 + l16][32 + quad * 8];
                O[c] = __builtin_amdgcn_mfma_f32_16x16x32_bf16(ap0, bv0, O[c], 0, 0, 0);
                O[c] = __builtin_amdgcn_mfma_f32_16x16x32_bf16(ap1, bv1, O[c], 0, 0, 0);
            }
        }

        #pragma unroll
        for (int c = 0; c < 4; ++c) {
            int d = h * 64 + c * 16 + l16;
            #pragma unroll
            for (int r = 0; r < 4; ++r) {
                int qrow = qs + qc + wave * 16 + quad * 4 + r;
                if (qrow < qe) {
                    size_t off = (size_t)qrow * HID + d;
                    Out[off] = (__bf16)((float)Vres[off] + O[c][r] / L[r]);
                }
            }
        }
    }
}

// ------------------------------ launcher -----------------------------------
extern "C" void kernel_launch(void* const* d_in, const int* in_sizes, int n_in,
                              void* d_out, int out_size, void* d_ws, size_t ws_size,
                              hipStream_t stream) {
    (void)in_sizes; (void)n_in; (void)out_size; (void)ws_size;

    const float* h_head = (const float*)d_in[0];
    const float* h_tail = (const float*)d_in[1];
    const int* batch_head = (const int*)d_in[2];
    const int* batch_tail = (const int*)d_in[3];
    const float* map_w = (const float*)d_in[4];
    const float* map_b = (const float*)d_in[5];
    const float* q1_w = (const float*)d_in[6];
    const float* q1_b = (const float*)d_in[7];
    const float* k1_w = (const float*)d_in[8];
    const float* k1_b = (const float*)d_in[9];
    const float* v1_w = (const float*)d_in[10];
    const float* v1_b = (const float*)d_in[11];
    const float* q2_w = (const float*)d_in[12];
    const float* q2_b = (const float*)d_in[13];
    const float* k2_w = (const float*)d_in[14];
    const float* k2_b = (const float*)d_in[15];
    const float* v2_w = (const float*)d_in[16];
    const float* v2_b = (const float*)d_in[17];
    const float* d1_w = (const float*)d_in[18];
    const float* d1_b = (const float*)d_in[19];
    const float* d2_w = (const float*)d_in[20];
    const float* d2_b = (const float*)d_in[21];

    float* out = (float*)d_out;

    const size_t SZ = (size_t)NTOK * HID;
    char* ws = (char*)d_ws;
    int* ranges   = (int*)ws;                            // 1 KB
    __bf16* hh_bf = (__bf16*)(ws + 1024);                // [4096][320]
    __bf16* ht_bf = hh_bf + (size_t)NTOK * 320;          // [4096][512]
    __bf16* q2T  = ht_bf + SZ;                           // [512][512] each
    __bf16* k2T  = q2T + 512 * 512;
    __bf16* v2T  = k2T + 512 * 512;
    __bf16* d1T  = v2T + 512 * 512;
    __bf16* d2T  = d1T + 512 * 512;
    __bf16* FqT  = d2T + 512 * 512;                      // [512][320] each
    __bf16* FkT  = FqT + 512 * 320;
    __bf16* FvT  = FkT + 512 * 320;
    __bf16* qh   = FvT + 512 * 320;                      // [4096][512] each
    __bf16* kh   = qh  + SZ;
    __bf16* vh   = kh  + SZ;
    __bf16* qt   = vh  + SZ;
    __bf16* kt   = qt  + SZ;
    __bf16* vt   = kt  + SZ;
    __bf16* ctxh = vt  + SZ;
    __bf16* ctxt = ctxh + SZ;

    // D1: all leaf work (casts, ranges, transposes, fold w/ bias row)
    PrepArgs pa;
    pa.h_head = h_head; pa.h_tail = h_tail;
    pa.bh = batch_head; pa.bt = batch_tail;
    pa.map_w = map_w; pa.map_b = map_b;
    pa.qkvw[0] = q1_w; pa.qkvw[1] = k1_w; pa.qkvw[2] = v1_w;
    const float* wsrc[5] = {q2_w, k2_w, v2_w, d1_w, d2_w};
    __bf16* wdst[5] = {q2T, k2T, v2T, d1T, d2T};
    for (int i = 0; i < 5; ++i) { pa.tsrc[i] = wsrc[i]; pa.tdst[i] = wdst[i]; }
    pa.hh_bf = hh_bf; pa.ht_bf = ht_bf;
    pa.F[0] = FqT; pa.F[1] = FkT; pa.F[2] = FvT;
    pa.ranges = ranges;
    fused_prep<<<dim3(512, 1, 8), dim3(256), 0, stream>>>(pa);

    // D2: ALL 6 qkv GEMMs (head Kp=320 via folded weights + plain q/k/v1 bias)
    {
        GemmJobs j;
        j.A[0] = hh_bf; j.W[0] = FqT; j.bias[0] = q1_b; j.C[0] = qh; j.Kp[0] = 320;
        j.A[1] = hh_bf; j.W[1] = FkT; j.bias[1] = k1_b; j.C[1] = kh; j.Kp[1] = 320;
        j.A[2] = hh_bf; j.W[2] = FvT; j.bias[2] = v1_b; j.C[2] = vh; j.Kp[2] = 320;
        j.A[3] = ht_bf; j.W[3] = q2T; j.bias[3] = q2_b; j.C[3] = qt; j.Kp[3] = 512;
        j.A[4] = ht_bf; j.W[4] = k2T; j.bias[4] = k2_b; j.C[4] = kt; j.Kp[4] = 512;
        j.A[5] = ht_bf; j.W[5] = v2T; j.bias[5] = v2_b; j.C[5] = vt; j.Kp[5] = 512;
        gemm128<__bf16><<<dim3(4, 32, 6), dim3(256), 0, stream>>>(j);
    }

    // D3: attention (both sides, one dispatch)
    attn_mfma<<<dim3(8, 64, 2), dim3(256), 0, stream>>>(
        qh, kt, vh, vt,
        qt, kh, vt, vh,
        ranges, ctxh, ctxt, NTOK, NTOK);

    // D4: output projections (fp32 into d_out)
    {
        GemmJobs j;
        j.A[0] = ctxh; j.W[0] = d1T; j.bias[0] = d1_b; j.C[0] = out;      j.Kp[0] = 512;
        j.A[1] = ctxt; j.W[1] = d2T; j.bias[1] = d2_b; j.C[1] = out + SZ; j.Kp[1] = 512;
        j.A[2] = ctxt; j.W[2] = d2T; j.bias[2] = d2_b; j.C[2] = out + SZ; j.Kp[2] = 512;
        j.A[3] = ctxt; j.W[3] = d2T; j.bias[3] = d2_b; j.C[3] = out + SZ; j.Kp[3] = 512;
        j.A[4] = ctxt; j.W[4] = d2T; j.bias[4] = d2_b; j.C[4] = out + SZ; j.Kp[4] = 512;
        j.A[5] = ctxt; j.W[5] = d2T; j.bias[5] = d2_b; j.C[5] = out + SZ; j.Kp[5] = 512;
        gemm128<float><<<dim3(4, 32, 2), dim3(256), 0, stream>>>(j);
    }
}